// Round 11
// baseline (639.685 us; speedup 1.0000x reference)
//
#include <hip/hip_runtime.h>

typedef unsigned short u16;
typedef unsigned int u32;
typedef __attribute__((ext_vector_type(8))) _Float16 f16x8;
typedef __attribute__((ext_vector_type(4))) float f32x4;

#define DEVINL __device__ __forceinline__
#define LOG2E 1.44269504f

DEVINL u16 f2h_u(float f) { _Float16 h = (_Float16)f; return __builtin_bit_cast(unsigned short, h); }
DEVINL float h2f_u(u16 h) { return (float)__builtin_bit_cast(_Float16, h); }
DEVINL float ex2(float x) { return __builtin_amdgcn_exp2f(x); }

DEVINL f16x8 ldfrag(const u16* p) {
    int4 d = *(const int4*)p;                 // ds_read_b128
    return __builtin_bit_cast(f16x8, d);
}
DEVINL f16x8 h8(int4 d) { return __builtin_bit_cast(f16x8, d); }

DEVINL void glds16(const u16* g, u16* l) {    // async global->LDS, 16B/lane
    __builtin_amdgcn_global_load_lds(
        (const __attribute__((address_space(1))) unsigned int*)g,
        (__attribute__((address_space(3))) unsigned int*)l, 16, 0, 0);
}

#define CFENCE  asm volatile("" ::: "memory")
#define VMCNT4  asm volatile("s_waitcnt vmcnt(4)" ::: "memory")
#define VMCNT0  asm volatile("s_waitcnt vmcnt(0)" ::: "memory")
#define LGKM0   asm volatile("s_waitcnt lgkmcnt(0)" ::: "memory")

static const long CN  = 256L * 4096L;   // 1M elems per batch-tensor
static const long PtE = 4096L * 4096L;  // 16M elems

// ---------------------------------------------------------------------------
// NT GEMM core v4b (A-direct, B fully staged): C[i,j] = sum_k A[i,k]*B[j,k].
// 256 thr = 4 waves (2x2); block 128x128; wave 64x64; BK=64.
// B: LDS via global_load_lds, 4 glds/wave/tile (wave w stages rows w*32..+31;
//    each glds = 8 rows). [r10 BUG: 2 glds/wave staged only half the tile ->
//    stale LDS -> NaN. Fixed: 4 glds, dOff=w*2048.]
//    3-bit chunk-XOR swizzle; 2-buf counted-vmcnt pipeline (r6 placement).
// A: direct global->register dwordx4 frags, double-buffered aR[2][8],
//    issued one iteration ahead (L2 latency hidden under MFMA+barrier).
// Per-iter issue order: [vmcnt(4); barrier; A(t+1) x8; ds_read; MFMA; lgkm0;
// barrier; B(t+2) x4]. Entry vmcnt(4): B(t+1) (newest 4) may fly; A(t) and
// B(t) (older) drained. LDS reads halved vs r6 core (8KB/wave/tile).
// ---------------------------------------------------------------------------
DEVINL void gemm_core(const u16* __restrict__ Ag, int lda,
                      const u16* __restrict__ Bg, int ldb,
                      int kOff, int kLen, u16* Bs, f32x4 (&acc)[4][4])
{
    int tid = threadIdx.x;
    int lane = tid & 63, w = tid >> 6;
    int wr = w >> 1, wc = w & 1;
    int kg = lane >> 4, rl = lane & 15;
    int l8 = lane >> 3, c8 = lane & 7;

    // B staging: wave w stages rows [w*32, w*32+32), 4 glds x 8 rows
    int srow = w * 32 + l8;
    int scol = (c8 ^ l8) * 8;                      // pre-swizzled source chunk
    const u16* bS = Bg + (size_t)srow * ldb + kOff + scol;
    int dOff = w * 2048;                           // elems: row w*32 at w*32*64

    int rl7 = rl & 7;
    int e0 = (kg ^ rl7) * 8;                       // swizzled chunk (half 0)
    int e1 = e0 ^ 32;                              // half 1
    int bRow = (wc * 64 + rl) * 64;

    // A direct per-lane row pointers (4 fragment rows)
    const u16* aP[4];
#pragma unroll
    for (int i = 0; i < 4; ++i)
        aP[i] = Ag + (size_t)(wr * 64 + i * 16 + rl) * lda + kOff + kg * 8;

    int4 aR[2][8];

    int nt = kLen >> 6;                            // kLen % 64 == 0, nt >= 2
    // prologue issue order (fixes vmcnt counts): B0(4), A0(8), B1(4)
#pragma unroll
    for (int q = 0; q < 4; ++q)
        glds16(bS + (size_t)q * 8 * ldb, Bs + dOff + q * 512);
    CFENCE;
#pragma unroll
    for (int i = 0; i < 4; ++i) {
        aR[0][i]     = *(const int4*)(aP[i]);
        aR[0][i + 4] = *(const int4*)(aP[i] + 32);
    }
    CFENCE;
#pragma unroll
    for (int q = 0; q < 4; ++q)
        glds16(bS + (size_t)q * 8 * ldb + 64, Bs + 8192 + dOff + q * 512);

    for (int t = 0; t < nt; ++t) {
        if (t + 1 < nt) { VMCNT4; } else { VMCNT0; }
        __builtin_amdgcn_s_barrier();
        CFENCE;
        if (t + 1 < nt) {                          // A(t+1) -> regs, early issue
            int nb = (t + 1) & 1;
#pragma unroll
            for (int i = 0; i < 4; ++i) {
                aR[nb][i]     = *(const int4*)(aP[i] + (size_t)(t + 1) * 64);
                aR[nb][i + 4] = *(const int4*)(aP[i] + (size_t)(t + 1) * 64 + 32);
            }
            CFENCE;
        }
        const u16* Bb = Bs + (t & 1) * 8192;
        f16x8 b0[4], b1[4];
#pragma unroll
        for (int j = 0; j < 4; ++j) b0[j] = ldfrag(&Bb[bRow + j * 1024 + e0]);
#pragma unroll
        for (int j = 0; j < 4; ++j) b1[j] = ldfrag(&Bb[bRow + j * 1024 + e1]);
        int cb = t & 1;
        __builtin_amdgcn_s_setprio(1);
#pragma unroll
        for (int i = 0; i < 4; ++i)
#pragma unroll
            for (int j = 0; j < 4; ++j)
                acc[i][j] = __builtin_amdgcn_mfma_f32_16x16x32_f16(h8(aR[cb][i]), b0[j], acc[i][j], 0, 0, 0);
#pragma unroll
        for (int i = 0; i < 4; ++i)
#pragma unroll
            for (int j = 0; j < 4; ++j)
                acc[i][j] = __builtin_amdgcn_mfma_f32_16x16x32_f16(h8(aR[cb][i + 4]), b1[j], acc[i][j], 0, 0, 0);
        __builtin_amdgcn_s_setprio(0);
        LGKM0;
        __builtin_amdgcn_s_barrier();
        CFENCE;
        if (t + 2 < nt) {                          // B(t+2) glds -> buf[t&1]
            const u16* bN = bS + (size_t)(t + 2) * 64;
            u16* Bd = Bs + (t & 1) * 8192 + dOff;
#pragma unroll
            for (int q = 0; q < 4; ++q)
                glds16(bN + (size_t)q * 8 * ldb, Bd + q * 512);
        }
    }
}

// merge (m,s) softmax partials, exp2 domain
DEVINL void mergeMS(float& m, float& s, float om, float os) {
    float nm = fmaxf(m, om);
    s = s * ex2((m - nm) * LOG2E) + os * ex2((om - nm) * LOG2E);
    m = nm;
}

// ---------------------------------------------------------------------------
// St GEMM + fused column-stats (r8 epilogue: direct scalar stores, two-pass
// reg stats on RTE-rounded values). Flat grid 4096, XCD-swizzled.
// ---------------------------------------------------------------------------
__launch_bounds__(256, 2)
__global__ void st_gemm(const u16* __restrict__ Kt, const u16* __restrict__ Ktth,
                        u16* __restrict__ StH,
                        float* __restrict__ pmax, float* __restrict__ psum)
{
    __shared__ __align__(16) u16 Bs[2 * 8192];
    int P = blockIdx.x;
    int L = (P & 7) * 512 + (P >> 3);
    int b = L >> 10, yb = (L >> 5) & 31, xb = L & 31;
    const u16* A = Kt   + (long)b * CN + (size_t)yb * 128 * 256;
    const u16* B = Ktth + (long)b * CN + (size_t)xb * 128 * 256;
    u16* out = StH + (long)b * PtE;
    int rowBase = yb * 128, colBase = xb * 128;

    f32x4 acc[4][4];
#pragma unroll
    for (int i = 0; i < 4; ++i)
#pragma unroll
        for (int j = 0; j < 4; ++j) acc[i][j] = (f32x4){0.f, 0.f, 0.f, 0.f};

    gemm_core(A, 256, B, 256, 0, 256, Bs, acc);

    int lane = threadIdx.x & 63, w = threadIdx.x >> 6;
    int wr = w >> 1, wc = w & 1, kg = lane >> 4, rl = lane & 15;

    // pass 0: round + scalar store + keep rounded f32
    float vr[4][4][4];
#pragma unroll
    for (int i = 0; i < 4; ++i) {
        int row0 = rowBase + wr * 64 + i * 16 + kg * 4;
#pragma unroll
        for (int j = 0; j < 4; ++j) {
            int col = colBase + wc * 64 + j * 16 + rl;
            f32x4 v = acc[i][j];
#pragma unroll
            for (int r = 0; r < 4; ++r) {
                u16 h = f2h_u(v[r]);
                out[(size_t)(row0 + r) * 4096 + col] = h;
                vr[i][j][r] = h2f_u(h);
            }
        }
    }
    // per-j max, then independent exp2 sums (ILP)
    float tm[4], ts[4];
#pragma unroll
    for (int j = 0; j < 4; ++j) {
        float m = vr[0][j][0];
#pragma unroll
        for (int i = 0; i < 4; ++i)
#pragma unroll
            for (int r = 0; r < 4; ++r) m = fmaxf(m, vr[i][j][r]);
        float mk = m * LOG2E, s = 0.f;
#pragma unroll
        for (int i = 0; i < 4; ++i)
#pragma unroll
            for (int r = 0; r < 4; ++r) s += ex2(fmaf(vr[i][j][r], LOG2E, -mk));
        tm[j] = m; ts[j] = s;
    }
#pragma unroll
    for (int j = 0; j < 4; ++j) {
        mergeMS(tm[j], ts[j], __shfl_xor(tm[j], 16, 64), __shfl_xor(ts[j], 16, 64));
        mergeMS(tm[j], ts[j], __shfl_xor(tm[j], 32, 64), __shfl_xor(ts[j], 32, 64));
    }
    float* red = (float*)Bs;             // Bs free after core
    __syncthreads();
    if (wr == 1 && lane < 16) {
#pragma unroll
        for (int j = 0; j < 4; ++j) {
            red[((wc * 4 + j) * 16 + rl) * 2 + 0] = tm[j];
            red[((wc * 4 + j) * 16 + rl) * 2 + 1] = ts[j];
        }
    }
    __syncthreads();
    if (wr == 0 && lane < 16) {
#pragma unroll
        for (int j = 0; j < 4; ++j) {
            mergeMS(tm[j], ts[j], red[((wc * 4 + j) * 16 + rl) * 2 + 0],
                                  red[((wc * 4 + j) * 16 + rl) * 2 + 1]);
            int col = colBase + wc * 64 + j * 16 + rl;
            long idx = ((long)b * 32 + yb) * 4096 + col;
            pmax[idx] = tm[j];
            psum[idx] = ts[j];
        }
    }
}

// fold 32 row-block partials -> cmK (= cmax*log2e), crcp
__global__ void stats_combine(const float* __restrict__ pmax, const float* __restrict__ psum,
                              float* __restrict__ cmK, float* __restrict__ crcp)
{
    int b = blockIdx.y;
    int col = blockIdx.x * 256 + threadIdx.x;
    const float* pm = pmax + (long)b * 32 * 4096 + col;
    const float* ps = psum + (long)b * 32 * 4096 + col;
    float m = -3.0e38f, s = 0.f;
    for (int i = 0; i < 32; ++i) mergeMS(m, s, pm[i * 4096], ps[i * 4096]);
    cmK[b * 4096 + col] = m * LOG2E;
    crcp[b * 4096 + col] = 1.f / s;
}

// in-place Pt[m,n] = fp16( exp2(St*log2e - cmK[n]) * crcp[n] ), 8 cols/thread
__global__ void pt8_kernel(u16* St, const float* __restrict__ cmK,
                           const float* __restrict__ crcp)
{
    int b = blockIdx.z;
    St += (long)b * PtE;
    cmK += b * 4096; crcp += b * 4096;
    int m = blockIdx.y;
    int c0 = (blockIdx.x * 256 + threadIdx.x) * 8;
    size_t o = (size_t)m * 4096 + c0;
    f16x8 hv = __builtin_bit_cast(f16x8, *(const int4*)(St + o));
    union { u16 q[8]; int4 v; } pk;
#pragma unroll
    for (int j = 0; j < 8; ++j)
        pk.q[j] = f2h_u(ex2(fmaf((float)hv[j], LOG2E, -cmK[c0 + j])) * crcp[c0 + j]);
    *(int4*)(St + o) = pk.v;
}

// ---------------------------------------------------------------------------
// PV apply: x_1 = gamma*(V . P^T) + src. Flat 512, XCD-swizzled (r7-proven).
// ---------------------------------------------------------------------------
__launch_bounds__(256, 2)
__global__ void pv_gemm(const u16* __restrict__ V2, const u16* __restrict__ Pt,
                        const float* __restrict__ g0p, const float* __restrict__ g1p,
                        const float* __restrict__ src0, const float* __restrict__ src1,
                        float* __restrict__ out0, float* __restrict__ out1)
{
    __shared__ __align__(16) u16 Bs[2 * 8192];
    int P = blockIdx.x;
    int L = (P & 7) * 64 + (P >> 3);
    int b = L >> 7, n = (L >> 2) & 31, y = (L >> 1) & 1, t = L & 1;
    const u16* A = V2 + ((long)b * 2 + t) * CN;
    const u16* B = Pt + (long)b * PtE;
    int rowBase = y * 128, colBase = n * 128;

    f32x4 acc[4][4];
#pragma unroll
    for (int i = 0; i < 4; ++i)
#pragma unroll
        for (int j = 0; j < 4; ++j) acc[i][j] = (f32x4){0.f, 0.f, 0.f, 0.f};

    gemm_core(A + (size_t)rowBase * 4096, 4096, B + (size_t)colBase * 4096, 4096,
              0, 4096, Bs, acc);

    float gamma = t ? *g1p : *g0p;       // after core: keeps in-loop vmcnt exact
    const float* src = (t ? src1 : src0) + (long)b * CN;
    float* out = (t ? out1 : out0) + (long)b * CN;
    int lane = threadIdx.x & 63, w = threadIdx.x >> 6;
    int wr = w >> 1, wc = w & 1, kg = lane >> 4, rl = lane & 15;
#pragma unroll
    for (int i = 0; i < 4; ++i) {
        int row0 = rowBase + wr * 64 + i * 16 + kg * 4;
#pragma unroll
        for (int j = 0; j < 4; ++j) {
            int col = colBase + wc * 64 + j * 16 + rl;
            f32x4 v = acc[i][j];
#pragma unroll
            for (int r = 0; r < 4; ++r) {
                int row = row0 + r;
                out[(size_t)row * 4096 + col] = gamma * v[r] + src[(size_t)row * 4096 + col];
            }
        }
    }
}

// split-K atomicAdd f32 (energy): z -> {bq=z>>zshift, slice}
__launch_bounds__(256, 2)
__global__ void gemm_splitk(const u16* __restrict__ A, int lda, long sAz,
                            const u16* __restrict__ B, int ldb, long sBz,
                            int splitK, int zshift,
                            float* __restrict__ outf, int ldo, long sOz)
{
    __shared__ __align__(16) u16 Bs[2 * 8192];
    int z = blockIdx.z;
    int bq = z >> zshift, s = z & ((1 << zshift) - 1);
    int kOff = s * splitK;
    A += sAz * bq; B += sBz * bq;
    long zo = sOz * bq;
    int rowBase = blockIdx.y * 128, colBase = blockIdx.x * 128;
    f32x4 acc[4][4];
#pragma unroll
    for (int i = 0; i < 4; ++i)
#pragma unroll
        for (int j = 0; j < 4; ++j) acc[i][j] = (f32x4){0.f, 0.f, 0.f, 0.f};

    gemm_core(A + (size_t)rowBase * lda, lda, B + (size_t)colBase * ldb, ldb, kOff, splitK, Bs, acc);

    int lane = threadIdx.x & 63, w = threadIdx.x >> 6;
    int wr = w >> 1, wc = w & 1, kg = lane >> 4, rl = lane & 15;
#pragma unroll
    for (int i = 0; i < 4; ++i) {
        int row0 = rowBase + wr * 64 + i * 16 + kg * 4;
#pragma unroll
        for (int j = 0; j < 4; ++j) {
            int col = colBase + wc * 64 + j * 16 + rl;
            f32x4 v = acc[i][j];
#pragma unroll
            for (int r = 0; r < 4; ++r)
                atomicAdd(&outf[zo + (size_t)(row0 + r) * ldo + col], v[r]);
        }
    }
}

// all 16 projections in one dispatch: z = b*4 + t, out[n][o] fp16 + bias
__launch_bounds__(256, 2)
__global__ void proj_all(const u16* __restrict__ xT, const u16* __restrict__ xthT,
                         const u16* __restrict__ wts,
                         const float* __restrict__ b0, const float* __restrict__ b1,
                         const float* __restrict__ b2, const float* __restrict__ b3,
                         u16* o0, u16* o1, u16* o2, u16* o3)
{
    __shared__ __align__(16) u16 Bs[2 * 8192];
    int z = blockIdx.z, b = z >> 2, t = z & 3;
    const u16* A = ((t & 1) ? xthT : xT) + (long)b * CN;
    const u16* B = wts + t * 65536;
    u16* out = t == 0 ? o0 + (long)b * CN : t == 1 ? o1 + (long)b * CN
             : t == 2 ? o2 + (long)b * 2 * CN : o3 + (long)b * 2 * CN;
    int rowBase = blockIdx.y * 128, colBase = blockIdx.x * 128;
    f32x4 acc[4][4];
#pragma unroll
    for (int i = 0; i < 4; ++i)
#pragma unroll
        for (int j = 0; j < 4; ++j) acc[i][j] = (f32x4){0.f, 0.f, 0.f, 0.f};

    gemm_core(A + (size_t)rowBase * 256, 256, B + (size_t)colBase * 256, 256, 0, 256, Bs, acc);

    const float* bias = t == 0 ? b0 : t == 1 ? b1 : t == 2 ? b2 : b3;
    int lane = threadIdx.x & 63, w = threadIdx.x >> 6;
    int wr = w >> 1, wc = w & 1, kg = lane >> 4, rl = lane & 15;
#pragma unroll
    for (int i = 0; i < 4; ++i) {
        int row0 = rowBase + wr * 64 + i * 16 + kg * 4;
#pragma unroll
        for (int j = 0; j < 4; ++j) {
            int col = colBase + wc * 64 + j * 16 + rl;
            f32x4 v = acc[i][j];
#pragma unroll
            for (int r = 0; r < 4; ++r)
                out[(size_t)(row0 + r) * 256 + col] = f2h_u(v[r] + bias[col]);
        }
    }
}

// channel apply: out = gamma*(simc . Vt2^T) + src; flat 512, XCD-swizzled.
__launch_bounds__(256, 2)
__global__ void ch_gemm(const u16* __restrict__ simcb, const u16* __restrict__ Vt2,
                        const float* __restrict__ g0p, const float* __restrict__ g1p,
                        const float* __restrict__ src0, const float* __restrict__ src1,
                        float* __restrict__ out0, float* __restrict__ out1)
{
    __shared__ __align__(16) u16 Bs[2 * 8192];
    int P = blockIdx.x;
    int L = (P & 7) * 64 + (P >> 3);
    int b = L >> 7, t = (L >> 6) & 1, n = (L >> 1) & 31, y = L & 1;
    const u16* A = simcb + (long)b * 65536;
    const u16* B = Vt2 + ((long)b * 2 + t) * CN;
    int rowBase = y * 128, colBase = n * 128;

    f32x4 acc[4][4];
#pragma unroll
    for (int i = 0; i < 4; ++i)
#pragma unroll
        for (int j = 0; j < 4; ++j) acc[i][j] = (f32x4){0.f, 0.f, 0.f, 0.f};

    gemm_core(A + (size_t)rowBase * 256, 256, B + (size_t)colBase * 256, 256, 0, 256, Bs, acc);

    float gamma = t ? *g1p : *g0p;
    const float* src = (t ? src1 : src0) + (long)b * CN;
    float* out = (t ? out1 : out0) + (long)b * CN;
    int lane = threadIdx.x & 63, w = threadIdx.x >> 6;
    int wr = w >> 1, wc = w & 1, kg = lane >> 4, rl = lane & 15;
#pragma unroll
    for (int i = 0; i < 4; ++i) {
        int row0 = rowBase + wr * 64 + i * 16 + kg * 4;
#pragma unroll
        for (int j = 0; j < 4; ++j) {
            int col = colBase + wc * 64 + j * 16 + rl;
            f32x4 v = acc[i][j];
#pragma unroll
            for (int r = 0; r < 4; ++r) {
                int row = row0 + r;
                out[(size_t)row * 4096 + col] = gamma * v[r] + src[(size_t)row * 4096 + col];
            }
        }
    }
}

// f32 [R][NC] -> fp16 [NC][R] transpose; z = 2 tensors x 4 batches
__global__ void tr_f32_h2(const float* __restrict__ in0, const float* __restrict__ in1,
                          u16* __restrict__ out0, u16* __restrict__ out1)
{
    int z = blockIdx.z, b = z & 3;
    const float* in = ((z >> 2) ? in1 : in0) + (long)b * CN;
    u16* out = ((z >> 2) ? out1 : out0) + (long)b * CN;
    __shared__ u16 s[64 * 65];
    int tx = threadIdx.x & 63, tw = threadIdx.x >> 6;
    int r0 = blockIdx.y * 64, c0 = blockIdx.x * 64;
#pragma unroll
    for (int p = 0; p < 16; ++p) {
        int r = tw + p * 4;
        s[tx * 65 + r] = f2h_u(in[(size_t)(r0 + r) * 4096 + c0 + tx]);
    }
    __syncthreads();
#pragma unroll
    for (int p = 0; p < 16; ++p) {
        int rr = tw + p * 4;
        out[(size_t)(c0 + rr) * 256 + r0 + tx] = s[rr * 65 + tx];
    }
}

// fp16 [R][NC] -> fp16 [NC][R]
__global__ void tr_h_h(const u16* __restrict__ in, u16* __restrict__ out,
                       int R, int NC_, long sIn, long sOut)
{
    in += (long)blockIdx.z * sIn; out += (long)blockIdx.z * sOut;
    __shared__ u16 s[64 * 65];
    int tx = threadIdx.x & 63, tw = threadIdx.x >> 6;
    int r0 = blockIdx.y * 64, c0 = blockIdx.x * 64;
#pragma unroll
    for (int p = 0; p < 16; ++p) {
        int r = tw + p * 4;
        s[tx * 65 + r] = in[(size_t)(r0 + r) * NC_ + c0 + tx];
    }
    __syncthreads();
#pragma unroll
    for (int p = 0; p < 16; ++p) {
        int rr = tw + p * 4;
        out[(size_t)(c0 + rr) * R + r0 + tx] = s[rr * 65 + tx];
    }
}

__global__ void cvt_w_kernel(const float* __restrict__ w0, const float* __restrict__ w1,
                             const float* __restrict__ w2, const float* __restrict__ w3,
                             u16* __restrict__ out)
{
    int i = blockIdx.x * 256 + threadIdx.x;
    const float* w = (i < 65536) ? w0 : (i < 131072) ? w1 : (i < 196608) ? w2 : w3;
    out[i] = f2h_u(w[i & 65535]);
}

DEVINL float blockReduce(float v, int op) {  // op 0 = max, 1 = sum; 256 threads
    __shared__ float s[4];
#pragma unroll
    for (int o = 32; o; o >>= 1) {
        float t = __shfl_xor(v, o, 64);
        v = op ? (v + t) : fmaxf(v, t);
    }
    __syncthreads();
    if ((threadIdx.x & 63) == 0) s[threadIdx.x >> 6] = v;
    __syncthreads();
    return op ? (s[0] + s[1] + s[2] + s[3]) : fmaxf(fmaxf(s[0], s[1]), fmaxf(s[2], s[3]));
}

// sim_c row softmax of (rowmax(E) - E) over d; E f32 [b][256][256]
__global__ void simc_kernel(const float* __restrict__ E, u16* __restrict__ simc)
{
    int bb = blockIdx.y;
    const float* Eb = E + bb * 65536;
    u16* sc = simc + bb * 65536;
    int c = blockIdx.x, d = threadIdx.x;
    float e = Eb[c * 256 + d];
    float rmax = blockReduce(e, 0);
    float v = rmax - e;
    float vmax = blockReduce(v, 0);
    float p = __expf(v - vmax);
    float s = blockReduce(p, 1);
    sc[c * 256 + d] = f2h_u(p / s);
}

extern "C" void kernel_launch(void* const* d_in, const int* in_sizes, int n_in,
                              void* d_out, int out_size, void* d_ws, size_t ws_size,
                              hipStream_t stream)
{
    const float* x      = (const float*)d_in[0];
    const float* xth    = (const float*)d_in[1];
    const float* Wk_rgb = (const float*)d_in[2];
    const float* bk_rgb = (const float*)d_in[3];
    const float* Wk_th  = (const float*)d_in[4];
    const float* bk_th  = (const float*)d_in[5];
    const float* Wv_rgb = (const float*)d_in[6];
    const float* bv_rgb = (const float*)d_in[7];
    const float* Wv_th  = (const float*)d_in[8];
    const float* bv_th  = (const float*)d_in[9];
    const float* g1r = (const float*)d_in[10];
    const float* g1t = (const float*)d_in[11];
    const float* g2r = (const float*)d_in[12];
    const float* g2t = (const float*)d_in[13];

    // ws carve-up (~176.5 MB)
    u16* wts   = (u16*)d_ws;             // [4][256][256] fp16
    u16* Kt    = wts + 4 * 65536;        // [4][4096][256] x_k^T (dead after st_gemm)
    u16* Ktth  = Kt + 4 * CN;
    u16* Vt2   = Ktth + 4 * CN;          // [4][2][4096][256]
    u16* V2    = Vt2 + 8 * CN;           // [4][2][256][4096]
    u16* StH   = V2 + 8 * CN;            // [4][4096][4096] fp16 logits -> P in place
    // small buffers alias dead-after-St Kt region (8 MB)
    u16* simc   = Kt;                    // [4][256][256] fp16
    float* E    = (float*)(Kt + 4 * 65536);  // [4][256][256] f32
    float* cmK  = E + 4 * 65536;         // [4][4096] cmax*log2e
    float* crcp = cmK + 4 * 4096;        // [4][4096]
    u16* xT    = StH;                    // alias: dead before first StH write
    u16* xthT  = xT + 4 * CN;

    float* outX2  = (float*)d_out;
    float* outXt2 = outX2 + 4 * CN;

    // softmax block-partials in d_out scratch (consumed before PV overwrites)
    float* pmax = outX2;                 // [4][32][4096]
    float* psum = pmax + 4 * 32 * 4096;  // [4][32][4096]

    cvt_w_kernel<<<1024, 256, 0, stream>>>(Wk_rgb, Wk_th, Wv_rgb, Wv_th, wts);
    tr_f32_h2<<<dim3(64, 4, 8), 256, 0, stream>>>(x, xth, xT, xthT);

    proj_all<<<dim3(2, 32, 16), 256, 0, stream>>>(xT, xthT, wts,
        bk_rgb, bk_th, bv_rgb, bv_th, Kt, Ktth, Vt2, Vt2 + CN);

    tr_h_h<<<dim3(4, 64, 8), 256, 0, stream>>>(Vt2, V2, 4096, 256, CN, CN);

    // St = K . K_th^T (fp16) + fused column stats
    st_gemm<<<4096, 256, 0, stream>>>(Kt, Ktth, StH, pmax, psum);
    stats_combine<<<dim3(16, 4), 256, 0, stream>>>(pmax, psum, cmK, crcp);
    pt8_kernel<<<dim3(2, 4096, 4), 256, 0, stream>>>(StH, cmK, crcp);

    // x_1 = gamma1 * (V @ P) + x
    pv_gemm<<<512, 256, 0, stream>>>(
        V2, StH, g1r, g1t, x, xth, outX2, outXt2);

    // energy[c,d] = sum_n Vth[c,n] V[d,n]; split-K (32x128) x 4 batches
    (void)hipMemsetAsync(E, 0, 4 * 65536 * sizeof(float), stream);
    gemm_splitk<<<dim3(2, 2, 128), 256, 0, stream>>>(
        V2 + CN, 4096, 2 * CN, V2, 4096, 2 * CN,
        128, 5, E, 256, 65536);
    simc_kernel<<<dim3(256, 4), 256, 0, stream>>>(E, simc);

    // x_2 = gamma2 * (simc @ V) + x_1   (in-place on d_out)
    ch_gemm<<<512, 256, 0, stream>>>(
        simc, Vt2, g2r, g2t, outX2, outXt2, outX2, outXt2);
}

// Round 12
// 383.826 us; speedup vs baseline: 1.6666x; 1.6666x over previous
//
#include <hip/hip_runtime.h>

typedef unsigned short u16;
typedef unsigned int u32;
typedef __attribute__((ext_vector_type(8))) _Float16 f16x8;
typedef __attribute__((ext_vector_type(4))) float f32x4;

#define DEVINL __device__ __forceinline__
#define LOG2E 1.44269504f

DEVINL u16 f2h_u(float f) { _Float16 h = (_Float16)f; return __builtin_bit_cast(unsigned short, h); }
DEVINL float h2f_u(u16 h) { return (float)__builtin_bit_cast(_Float16, h); }
DEVINL float ex2(float x) { return __builtin_amdgcn_exp2f(x); }

DEVINL f16x8 ldfrag(const u16* p) {
    int4 d = *(const int4*)p;                 // ds_read_b128
    return __builtin_bit_cast(f16x8, d);
}
DEVINL f16x8 h8(int4 d) { return __builtin_bit_cast(f16x8, d); }

DEVINL void glds16(const u16* g, u16* l) {    // async global->LDS, 16B/lane
    __builtin_amdgcn_global_load_lds(
        (const __attribute__((address_space(1))) unsigned int*)g,
        (__attribute__((address_space(3))) unsigned int*)l, 16, 0, 0);
}

#define CFENCE  asm volatile("" ::: "memory")
#define VMCNT4  asm volatile("s_waitcnt vmcnt(4)" ::: "memory")
#define VMCNT0  asm volatile("s_waitcnt vmcnt(0)" ::: "memory")
#define LGKM0   asm volatile("s_waitcnt lgkmcnt(0)" ::: "memory")

static const long CN  = 256L * 4096L;   // 1M elems per batch-tensor
static const long PtE = 4096L * 4096L;  // 16M elems

// A(t) -> named register buffer (ALL indices compile-time after inlining).
// [r11 BUG: aR[2][8] with runtime parity index -> scratch-allocated ->
//  1.1 GB spill traffic, VGPR=64. Fix per rule #20: x2-unrolled loop with
//  named aR0/aR1 and reference-to-array helpers.]
DEVINL void loadA(int4 (&dst)[8], const u16* const (&aP)[4], long off) {
#pragma unroll
    for (int i = 0; i < 4; ++i) {
        dst[i]     = *(const int4*)(aP[i] + off);
        dst[i + 4] = *(const int4*)(aP[i] + off + 32);
    }
}

DEVINL void mfmaStep(const int4 (&aC)[8], const u16* Bb, int bRow, int e0, int e1,
                     f32x4 (&acc)[4][4]) {
    f16x8 b0[4], b1[4];
#pragma unroll
    for (int j = 0; j < 4; ++j) b0[j] = ldfrag(&Bb[bRow + j * 1024 + e0]);
#pragma unroll
    for (int j = 0; j < 4; ++j) b1[j] = ldfrag(&Bb[bRow + j * 1024 + e1]);
    __builtin_amdgcn_s_setprio(1);
#pragma unroll
    for (int i = 0; i < 4; ++i)
#pragma unroll
        for (int j = 0; j < 4; ++j)
            acc[i][j] = __builtin_amdgcn_mfma_f32_16x16x32_f16(h8(aC[i]), b0[j], acc[i][j], 0, 0, 0);
#pragma unroll
    for (int i = 0; i < 4; ++i)
#pragma unroll
        for (int j = 0; j < 4; ++j)
            acc[i][j] = __builtin_amdgcn_mfma_f32_16x16x32_f16(h8(aC[i + 4]), b1[j], acc[i][j], 0, 0, 0);
    __builtin_amdgcn_s_setprio(0);
}

// ---------------------------------------------------------------------------
// NT GEMM core v4c (A-direct, static regs): C[i,j] = sum_k A[i,k]*B[j,k].
// 256 thr = 4 waves (2x2); block 128x128; wave 64x64; BK=64.
// B: LDS via global_load_lds (4 glds/wave/tile, rows w*32..+31), 3-bit
//    chunk-XOR swizzle, 2-buf counted-vmcnt pipeline (r6/r11 placement).
// A: direct global->register dwordx4 frags, double-buffered in NAMED
//    aR0/aR1, issued one iteration ahead. K-loop unrolled x2 so buffer
//    choice and B-buf parity are compile-time.
// ---------------------------------------------------------------------------
DEVINL void gemm_core(const u16* __restrict__ Ag, int lda,
                      const u16* __restrict__ Bg, int ldb,
                      int kOff, int kLen, u16* Bs, f32x4 (&acc)[4][4])
{
    int tid = threadIdx.x;
    int lane = tid & 63, w = tid >> 6;
    int wr = w >> 1, wc = w & 1;
    int kg = lane >> 4, rl = lane & 15;
    int l8 = lane >> 3, c8 = lane & 7;

    // B staging: wave w stages rows [w*32, w*32+32), 4 glds x 8 rows
    int srow = w * 32 + l8;
    int scol = (c8 ^ l8) * 8;                      // pre-swizzled source chunk
    const u16* bS = Bg + (size_t)srow * ldb + kOff + scol;
    int dOff = w * 2048;

    int rl7 = rl & 7;
    int e0 = (kg ^ rl7) * 8;                       // swizzled chunk (half 0)
    int e1 = e0 ^ 32;                              // half 1
    int bRow = (wc * 64 + rl) * 64;

    const u16* aP[4];
#pragma unroll
    for (int i = 0; i < 4; ++i)
        aP[i] = Ag + (size_t)(wr * 64 + i * 16 + rl) * lda + kOff + kg * 8;

    int4 aR0[8], aR1[8];

    int nt = kLen >> 6;                            // kLen % 128 == 0 -> nt even, >= 2
    // prologue issue order (fixes vmcnt counts): B0(4), A0(8), B1(4)
#pragma unroll
    for (int q = 0; q < 4; ++q)
        glds16(bS + (size_t)q * 8 * ldb, Bs + dOff + q * 512);
    CFENCE;
    loadA(aR0, aP, 0);
    CFENCE;
#pragma unroll
    for (int q = 0; q < 4; ++q)
        glds16(bS + (size_t)q * 8 * ldb + 64, Bs + 8192 + dOff + q * 512);

    for (int t = 0; t < nt; t += 2) {
        // ---- even iter (parity 0): compute aR0 / B buf0; prefetch A -> aR1
        VMCNT4;                                    // t+1 < nt always (nt even)
        __builtin_amdgcn_s_barrier();
        CFENCE;
        loadA(aR1, aP, (long)(t + 1) * 64);
        CFENCE;
        mfmaStep(aR0, Bs, bRow, e0, e1, acc);
        LGKM0;
        __builtin_amdgcn_s_barrier();
        CFENCE;
        if (t + 2 < nt) {
            const u16* bN = bS + (size_t)(t + 2) * 64;
#pragma unroll
            for (int q = 0; q < 4; ++q)
                glds16(bN + (size_t)q * 8 * ldb, Bs + dOff + q * 512);
        }
        // ---- odd iter (parity 1): compute aR1 / B buf1; prefetch A -> aR0
        bool last = (t + 2 >= nt);
        if (!last) { VMCNT4; } else { VMCNT0; }
        __builtin_amdgcn_s_barrier();
        CFENCE;
        if (!last) {
            loadA(aR0, aP, (long)(t + 2) * 64);
            CFENCE;
        }
        mfmaStep(aR1, Bs + 8192, bRow, e0, e1, acc);
        LGKM0;
        __builtin_amdgcn_s_barrier();
        CFENCE;
        if (t + 3 < nt) {
            const u16* bN = bS + (size_t)(t + 3) * 64;
#pragma unroll
            for (int q = 0; q < 4; ++q)
                glds16(bN + (size_t)q * 8 * ldb, Bs + 8192 + dOff + q * 512);
        }
    }
}

// merge (m,s) softmax partials, exp2 domain
DEVINL void mergeMS(float& m, float& s, float om, float os) {
    float nm = fmaxf(m, om);
    s = s * ex2((m - nm) * LOG2E) + os * ex2((om - nm) * LOG2E);
    m = nm;
}

// ---------------------------------------------------------------------------
// St GEMM + fused column-stats (r8 epilogue). Flat grid 4096, XCD-swizzled.
// ---------------------------------------------------------------------------
__launch_bounds__(256, 2)
__global__ void st_gemm(const u16* __restrict__ Kt, const u16* __restrict__ Ktth,
                        u16* __restrict__ StH,
                        float* __restrict__ pmax, float* __restrict__ psum)
{
    __shared__ __align__(16) u16 Bs[2 * 8192];
    int P = blockIdx.x;
    int L = (P & 7) * 512 + (P >> 3);
    int b = L >> 10, yb = (L >> 5) & 31, xb = L & 31;
    const u16* A = Kt   + (long)b * CN + (size_t)yb * 128 * 256;
    const u16* B = Ktth + (long)b * CN + (size_t)xb * 128 * 256;
    u16* out = StH + (long)b * PtE;
    int rowBase = yb * 128, colBase = xb * 128;

    f32x4 acc[4][4];
#pragma unroll
    for (int i = 0; i < 4; ++i)
#pragma unroll
        for (int j = 0; j < 4; ++j) acc[i][j] = (f32x4){0.f, 0.f, 0.f, 0.f};

    gemm_core(A, 256, B, 256, 0, 256, Bs, acc);

    int lane = threadIdx.x & 63, w = threadIdx.x >> 6;
    int wr = w >> 1, wc = w & 1, kg = lane >> 4, rl = lane & 15;

    float vr[4][4][4];
#pragma unroll
    for (int i = 0; i < 4; ++i) {
        int row0 = rowBase + wr * 64 + i * 16 + kg * 4;
#pragma unroll
        for (int j = 0; j < 4; ++j) {
            int col = colBase + wc * 64 + j * 16 + rl;
            f32x4 v = acc[i][j];
#pragma unroll
            for (int r = 0; r < 4; ++r) {
                u16 h = f2h_u(v[r]);
                out[(size_t)(row0 + r) * 4096 + col] = h;
                vr[i][j][r] = h2f_u(h);
            }
        }
    }
    float tm[4], ts[4];
#pragma unroll
    for (int j = 0; j < 4; ++j) {
        float m = vr[0][j][0];
#pragma unroll
        for (int i = 0; i < 4; ++i)
#pragma unroll
            for (int r = 0; r < 4; ++r) m = fmaxf(m, vr[i][j][r]);
        float mk = m * LOG2E, s = 0.f;
#pragma unroll
        for (int i = 0; i < 4; ++i)
#pragma unroll
            for (int r = 0; r < 4; ++r) s += ex2(fmaf(vr[i][j][r], LOG2E, -mk));
        tm[j] = m; ts[j] = s;
    }
#pragma unroll
    for (int j = 0; j < 4; ++j) {
        mergeMS(tm[j], ts[j], __shfl_xor(tm[j], 16, 64), __shfl_xor(ts[j], 16, 64));
        mergeMS(tm[j], ts[j], __shfl_xor(tm[j], 32, 64), __shfl_xor(ts[j], 32, 64));
    }
    float* red = (float*)Bs;             // Bs free after core
    __syncthreads();
    if (wr == 1 && lane < 16) {
#pragma unroll
        for (int j = 0; j < 4; ++j) {
            red[((wc * 4 + j) * 16 + rl) * 2 + 0] = tm[j];
            red[((wc * 4 + j) * 16 + rl) * 2 + 1] = ts[j];
        }
    }
    __syncthreads();
    if (wr == 0 && lane < 16) {
#pragma unroll
        for (int j = 0; j < 4; ++j) {
            mergeMS(tm[j], ts[j], red[((wc * 4 + j) * 16 + rl) * 2 + 0],
                                  red[((wc * 4 + j) * 16 + rl) * 2 + 1]);
            int col = colBase + wc * 64 + j * 16 + rl;
            long idx = ((long)b * 32 + yb) * 4096 + col;
            pmax[idx] = tm[j];
            psum[idx] = ts[j];
        }
    }
}

// fold 32 row-block partials -> cmK (= cmax*log2e), crcp
__global__ void stats_combine(const float* __restrict__ pmax, const float* __restrict__ psum,
                              float* __restrict__ cmK, float* __restrict__ crcp)
{
    int b = blockIdx.y;
    int col = blockIdx.x * 256 + threadIdx.x;
    const float* pm = pmax + (long)b * 32 * 4096 + col;
    const float* ps = psum + (long)b * 32 * 4096 + col;
    float m = -3.0e38f, s = 0.f;
    for (int i = 0; i < 32; ++i) mergeMS(m, s, pm[i * 4096], ps[i * 4096]);
    cmK[b * 4096 + col] = m * LOG2E;
    crcp[b * 4096 + col] = 1.f / s;
}

// in-place Pt[m,n] = fp16( exp2(St*log2e - cmK[n]) * crcp[n] ), 8 cols/thread
__global__ void pt8_kernel(u16* St, const float* __restrict__ cmK,
                           const float* __restrict__ crcp)
{
    int b = blockIdx.z;
    St += (long)b * PtE;
    cmK += b * 4096; crcp += b * 4096;
    int m = blockIdx.y;
    int c0 = (blockIdx.x * 256 + threadIdx.x) * 8;
    size_t o = (size_t)m * 4096 + c0;
    f16x8 hv = __builtin_bit_cast(f16x8, *(const int4*)(St + o));
    union { u16 q[8]; int4 v; } pk;
#pragma unroll
    for (int j = 0; j < 8; ++j)
        pk.q[j] = f2h_u(ex2(fmaf((float)hv[j], LOG2E, -cmK[c0 + j])) * crcp[c0 + j]);
    *(int4*)(St + o) = pk.v;
}

// ---------------------------------------------------------------------------
// PV apply: x_1 = gamma*(V . P^T) + src. Flat 512, XCD-swizzled (r7-proven).
// ---------------------------------------------------------------------------
__launch_bounds__(256, 2)
__global__ void pv_gemm(const u16* __restrict__ V2, const u16* __restrict__ Pt,
                        const float* __restrict__ g0p, const float* __restrict__ g1p,
                        const float* __restrict__ src0, const float* __restrict__ src1,
                        float* __restrict__ out0, float* __restrict__ out1)
{
    __shared__ __align__(16) u16 Bs[2 * 8192];
    int P = blockIdx.x;
    int L = (P & 7) * 64 + (P >> 3);
    int b = L >> 7, n = (L >> 2) & 31, y = (L >> 1) & 1, t = L & 1;
    const u16* A = V2 + ((long)b * 2 + t) * CN;
    const u16* B = Pt + (long)b * PtE;
    int rowBase = y * 128, colBase = n * 128;

    f32x4 acc[4][4];
#pragma unroll
    for (int i = 0; i < 4; ++i)
#pragma unroll
        for (int j = 0; j < 4; ++j) acc[i][j] = (f32x4){0.f, 0.f, 0.f, 0.f};

    gemm_core(A + (size_t)rowBase * 4096, 4096, B + (size_t)colBase * 4096, 4096,
              0, 4096, Bs, acc);

    float gamma = t ? *g1p : *g0p;       // after core: keeps in-loop vmcnt exact
    const float* src = (t ? src1 : src0) + (long)b * CN;
    float* out = (t ? out1 : out0) + (long)b * CN;
    int lane = threadIdx.x & 63, w = threadIdx.x >> 6;
    int wr = w >> 1, wc = w & 1, kg = lane >> 4, rl = lane & 15;
#pragma unroll
    for (int i = 0; i < 4; ++i) {
        int row0 = rowBase + wr * 64 + i * 16 + kg * 4;
#pragma unroll
        for (int j = 0; j < 4; ++j) {
            int col = colBase + wc * 64 + j * 16 + rl;
            f32x4 v = acc[i][j];
#pragma unroll
            for (int r = 0; r < 4; ++r) {
                int row = row0 + r;
                out[(size_t)row * 4096 + col] = gamma * v[r] + src[(size_t)row * 4096 + col];
            }
        }
    }
}

// split-K atomicAdd f32 (energy): z -> {bq=z>>zshift, slice}
__launch_bounds__(256, 2)
__global__ void gemm_splitk(const u16* __restrict__ A, int lda, long sAz,
                            const u16* __restrict__ B, int ldb, long sBz,
                            int splitK, int zshift,
                            float* __restrict__ outf, int ldo, long sOz)
{
    __shared__ __align__(16) u16 Bs[2 * 8192];
    int z = blockIdx.z;
    int bq = z >> zshift, s = z & ((1 << zshift) - 1);
    int kOff = s * splitK;
    A += sAz * bq; B += sBz * bq;
    long zo = sOz * bq;
    int rowBase = blockIdx.y * 128, colBase = blockIdx.x * 128;
    f32x4 acc[4][4];
#pragma unroll
    for (int i = 0; i < 4; ++i)
#pragma unroll
        for (int j = 0; j < 4; ++j) acc[i][j] = (f32x4){0.f, 0.f, 0.f, 0.f};

    gemm_core(A + (size_t)rowBase * lda, lda, B + (size_t)colBase * ldb, ldb, kOff, splitK, Bs, acc);

    int lane = threadIdx.x & 63, w = threadIdx.x >> 6;
    int wr = w >> 1, wc = w & 1, kg = lane >> 4, rl = lane & 15;
#pragma unroll
    for (int i = 0; i < 4; ++i) {
        int row0 = rowBase + wr * 64 + i * 16 + kg * 4;
#pragma unroll
        for (int j = 0; j < 4; ++j) {
            int col = colBase + wc * 64 + j * 16 + rl;
            f32x4 v = acc[i][j];
#pragma unroll
            for (int r = 0; r < 4; ++r)
                atomicAdd(&outf[zo + (size_t)(row0 + r) * ldo + col], v[r]);
        }
    }
}

// all 16 projections in one dispatch: z = b*4 + t, out[n][o] fp16 + bias
__launch_bounds__(256, 2)
__global__ void proj_all(const u16* __restrict__ xT, const u16* __restrict__ xthT,
                         const u16* __restrict__ wts,
                         const float* __restrict__ b0, const float* __restrict__ b1,
                         const float* __restrict__ b2, const float* __restrict__ b3,
                         u16* o0, u16* o1, u16* o2, u16* o3)
{
    __shared__ __align__(16) u16 Bs[2 * 8192];
    int z = blockIdx.z, b = z >> 2, t = z & 3;
    const u16* A = ((t & 1) ? xthT : xT) + (long)b * CN;
    const u16* B = wts + t * 65536;
    u16* out = t == 0 ? o0 + (long)b * CN : t == 1 ? o1 + (long)b * CN
             : t == 2 ? o2 + (long)b * 2 * CN : o3 + (long)b * 2 * CN;
    int rowBase = blockIdx.y * 128, colBase = blockIdx.x * 128;
    f32x4 acc[4][4];
#pragma unroll
    for (int i = 0; i < 4; ++i)
#pragma unroll
        for (int j = 0; j < 4; ++j) acc[i][j] = (f32x4){0.f, 0.f, 0.f, 0.f};

    gemm_core(A + (size_t)rowBase * 256, 256, B + (size_t)colBase * 256, 256, 0, 256, Bs, acc);

    const float* bias = t == 0 ? b0 : t == 1 ? b1 : t == 2 ? b2 : b3;
    int lane = threadIdx.x & 63, w = threadIdx.x >> 6;
    int wr = w >> 1, wc = w & 1, kg = lane >> 4, rl = lane & 15;
#pragma unroll
    for (int i = 0; i < 4; ++i) {
        int row0 = rowBase + wr * 64 + i * 16 + kg * 4;
#pragma unroll
        for (int j = 0; j < 4; ++j) {
            int col = colBase + wc * 64 + j * 16 + rl;
            f32x4 v = acc[i][j];
#pragma unroll
            for (int r = 0; r < 4; ++r)
                out[(size_t)(row0 + r) * 256 + col] = f2h_u(v[r] + bias[col]);
        }
    }
}

// channel apply: out = gamma*(simc . Vt2^T) + src; flat 512, XCD-swizzled.
__launch_bounds__(256, 2)
__global__ void ch_gemm(const u16* __restrict__ simcb, const u16* __restrict__ Vt2,
                        const float* __restrict__ g0p, const float* __restrict__ g1p,
                        const float* __restrict__ src0, const float* __restrict__ src1,
                        float* __restrict__ out0, float* __restrict__ out1)
{
    __shared__ __align__(16) u16 Bs[2 * 8192];
    int P = blockIdx.x;
    int L = (P & 7) * 64 + (P >> 3);
    int b = L >> 7, t = (L >> 6) & 1, n = (L >> 1) & 31, y = L & 1;
    const u16* A = simcb + (long)b * 65536;
    const u16* B = Vt2 + ((long)b * 2 + t) * CN;
    int rowBase = y * 128, colBase = n * 128;

    f32x4 acc[4][4];
#pragma unroll
    for (int i = 0; i < 4; ++i)
#pragma unroll
        for (int j = 0; j < 4; ++j) acc[i][j] = (f32x4){0.f, 0.f, 0.f, 0.f};

    gemm_core(A + (size_t)rowBase * 256, 256, B + (size_t)colBase * 256, 256, 0, 256, Bs, acc);

    float gamma = t ? *g1p : *g0p;
    const float* src = (t ? src1 : src0) + (long)b * CN;
    float* out = (t ? out1 : out0) + (long)b * CN;
    int lane = threadIdx.x & 63, w = threadIdx.x >> 6;
    int wr = w >> 1, wc = w & 1, kg = lane >> 4, rl = lane & 15;
#pragma unroll
    for (int i = 0; i < 4; ++i) {
        int row0 = rowBase + wr * 64 + i * 16 + kg * 4;
#pragma unroll
        for (int j = 0; j < 4; ++j) {
            int col = colBase + wc * 64 + j * 16 + rl;
            f32x4 v = acc[i][j];
#pragma unroll
            for (int r = 0; r < 4; ++r) {
                int row = row0 + r;
                out[(size_t)row * 4096 + col] = gamma * v[r] + src[(size_t)row * 4096 + col];
            }
        }
    }
}

// f32 [R][NC] -> fp16 [NC][R] transpose; z = 2 tensors x 4 batches
__global__ void tr_f32_h2(const float* __restrict__ in0, const float* __restrict__ in1,
                          u16* __restrict__ out0, u16* __restrict__ out1)
{
    int z = blockIdx.z, b = z & 3;
    const float* in = ((z >> 2) ? in1 : in0) + (long)b * CN;
    u16* out = ((z >> 2) ? out1 : out0) + (long)b * CN;
    __shared__ u16 s[64 * 65];
    int tx = threadIdx.x & 63, tw = threadIdx.x >> 6;
    int r0 = blockIdx.y * 64, c0 = blockIdx.x * 64;
#pragma unroll
    for (int p = 0; p < 16; ++p) {
        int r = tw + p * 4;
        s[tx * 65 + r] = f2h_u(in[(size_t)(r0 + r) * 4096 + c0 + tx]);
    }
    __syncthreads();
#pragma unroll
    for (int p = 0; p < 16; ++p) {
        int rr = tw + p * 4;
        out[(size_t)(c0 + rr) * 256 + r0 + tx] = s[rr * 65 + tx];
    }
}

// fp16 [R][NC] -> fp16 [NC][R]
__global__ void tr_h_h(const u16* __restrict__ in, u16* __restrict__ out,
                       int R, int NC_, long sIn, long sOut)
{
    in += (long)blockIdx.z * sIn; out += (long)blockIdx.z * sOut;
    __shared__ u16 s[64 * 65];
    int tx = threadIdx.x & 63, tw = threadIdx.x >> 6;
    int r0 = blockIdx.y * 64, c0 = blockIdx.x * 64;
#pragma unroll
    for (int p = 0; p < 16; ++p) {
        int r = tw + p * 4;
        s[tx * 65 + r] = in[(size_t)(r0 + r) * NC_ + c0 + tx];
    }
    __syncthreads();
#pragma unroll
    for (int p = 0; p < 16; ++p) {
        int rr = tw + p * 4;
        out[(size_t)(c0 + rr) * R + r0 + tx] = s[rr * 65 + tx];
    }
}

__global__ void cvt_w_kernel(const float* __restrict__ w0, const float* __restrict__ w1,
                             const float* __restrict__ w2, const float* __restrict__ w3,
                             u16* __restrict__ out)
{
    int i = blockIdx.x * 256 + threadIdx.x;
    const float* w = (i < 65536) ? w0 : (i < 131072) ? w1 : (i < 196608) ? w2 : w3;
    out[i] = f2h_u(w[i & 65535]);
}

DEVINL float blockReduce(float v, int op) {  // op 0 = max, 1 = sum; 256 threads
    __shared__ float s[4];
#pragma unroll
    for (int o = 32; o; o >>= 1) {
        float t = __shfl_xor(v, o, 64);
        v = op ? (v + t) : fmaxf(v, t);
    }
    __syncthreads();
    if ((threadIdx.x & 63) == 0) s[threadIdx.x >> 6] = v;
    __syncthreads();
    return op ? (s[0] + s[1] + s[2] + s[3]) : fmaxf(fmaxf(s[0], s[1]), fmaxf(s[2], s[3]));
}

// sim_c row softmax of (rowmax(E) - E) over d; E f32 [b][256][256]
__global__ void simc_kernel(const float* __restrict__ E, u16* __restrict__ simc)
{
    int bb = blockIdx.y;
    const float* Eb = E + bb * 65536;
    u16* sc = simc + bb * 65536;
    int c = blockIdx.x, d = threadIdx.x;
    float e = Eb[c * 256 + d];
    float rmax = blockReduce(e, 0);
    float v = rmax - e;
    float vmax = blockReduce(v, 0);
    float p = __expf(v - vmax);
    float s = blockReduce(p, 1);
    sc[c * 256 + d] = f2h_u(p / s);
}

extern "C" void kernel_launch(void* const* d_in, const int* in_sizes, int n_in,
                              void* d_out, int out_size, void* d_ws, size_t ws_size,
                              hipStream_t stream)
{
    const float* x      = (const float*)d_in[0];
    const float* xth    = (const float*)d_in[1];
    const float* Wk_rgb = (const float*)d_in[2];
    const float* bk_rgb = (const float*)d_in[3];
    const float* Wk_th  = (const float*)d_in[4];
    const float* bk_th  = (const float*)d_in[5];
    const float* Wv_rgb = (const float*)d_in[6];
    const float* bv_rgb = (const float*)d_in[7];
    const float* Wv_th  = (const float*)d_in[8];
    const float* bv_th  = (const float*)d_in[9];
    const float* g1r = (const float*)d_in[10];
    const float* g1t = (const float*)d_in[11];
    const float* g2r = (const float*)d_in[12];
    const float* g2t = (const float*)d_in[13];

    // ws carve-up (~176.5 MB)
    u16* wts   = (u16*)d_ws;             // [4][256][256] fp16
    u16* Kt    = wts + 4 * 65536;        // [4][4096][256] x_k^T (dead after st_gemm)
    u16* Ktth  = Kt + 4 * CN;
    u16* Vt2   = Ktth + 4 * CN;          // [4][2][4096][256]
    u16* V2    = Vt2 + 8 * CN;           // [4][2][256][4096]
    u16* StH   = V2 + 8 * CN;            // [4][4096][4096] fp16 logits -> P in place
    // small buffers alias dead-after-St Kt region (8 MB)
    u16* simc   = Kt;                    // [4][256][256] fp16
    float* E    = (float*)(Kt + 4 * 65536);  // [4][256][256] f32
    float* cmK  = E + 4 * 65536;         // [4][4096] cmax*log2e
    float* crcp = cmK + 4 * 4096;        // [4][4096]
    u16* xT    = StH;                    // alias: dead before first StH write
    u16* xthT  = xT + 4 * CN;

    float* outX2  = (float*)d_out;
    float* outXt2 = outX2 + 4 * CN;

    // softmax block-partials in d_out scratch (consumed before PV overwrites)
    float* pmax = outX2;                 // [4][32][4096]
    float* psum = pmax + 4 * 32 * 4096;  // [4][32][4096]

    cvt_w_kernel<<<1024, 256, 0, stream>>>(Wk_rgb, Wk_th, Wv_rgb, Wv_th, wts);
    tr_f32_h2<<<dim3(64, 4, 8), 256, 0, stream>>>(x, xth, xT, xthT);

    proj_all<<<dim3(2, 32, 16), 256, 0, stream>>>(xT, xthT, wts,
        bk_rgb, bk_th, bv_rgb, bv_th, Kt, Ktth, Vt2, Vt2 + CN);

    tr_h_h<<<dim3(4, 64, 8), 256, 0, stream>>>(Vt2, V2, 4096, 256, CN, CN);

    // St = K . K_th^T (fp16) + fused column stats
    st_gemm<<<4096, 256, 0, stream>>>(Kt, Ktth, StH, pmax, psum);
    stats_combine<<<dim3(16, 4), 256, 0, stream>>>(pmax, psum, cmK, crcp);
    pt8_kernel<<<dim3(2, 4096, 4), 256, 0, stream>>>(StH, cmK, crcp);

    // x_1 = gamma1 * (V @ P) + x
    pv_gemm<<<512, 256, 0, stream>>>(
        V2, StH, g1r, g1t, x, xth, outX2, outXt2);

    // energy[c,d] = sum_n Vth[c,n] V[d,n]; split-K (32x128) x 4 batches
    (void)hipMemsetAsync(E, 0, 4 * 65536 * sizeof(float), stream);
    gemm_splitk<<<dim3(2, 2, 128), 256, 0, stream>>>(
        V2 + CN, 4096, 2 * CN, V2, 4096, 2 * CN,
        128, 5, E, 256, 65536);
    simc_kernel<<<dim3(256, 4), 256, 0, stream>>>(E, simc);

    // x_2 = gamma2 * (simc @ V) + x_1   (in-place on d_out)
    ch_gemm<<<512, 256, 0, stream>>>(
        simc, Vt2, g2r, g2t, outX2, outXt2, outX2, outXt2);
}

// Round 13
// 269.555 us; speedup vs baseline: 2.3731x; 1.4239x over previous
//
#include <hip/hip_runtime.h>

typedef unsigned short u16;
typedef __attribute__((ext_vector_type(8))) _Float16 f16x8;
typedef __attribute__((ext_vector_type(4))) float f32x4;

#define DEVINL __device__ __forceinline__

DEVINL u16 f2h_u(float f) { _Float16 h = (_Float16)f; return __builtin_bit_cast(unsigned short, h); }
DEVINL float h2f_u(u16 h) { return (float)__builtin_bit_cast(_Float16, h); }

DEVINL f16x8 ldfrag(const u16* p) {
    int4 d = *(const int4*)p;                 // ds_read_b128
    return __builtin_bit_cast(f16x8, d);
}

DEVINL void glds16(const u16* g, u16* l) {    // async global->LDS, 16B/lane
    __builtin_amdgcn_global_load_lds(
        (const __attribute__((address_space(1))) unsigned int*)g,
        (__attribute__((address_space(3))) unsigned int*)l, 16, 0, 0);
}

#define CFENCE asm volatile("" ::: "memory")
#define VMCNT8 asm volatile("s_waitcnt vmcnt(8)" ::: "memory")
#define VMCNT0 asm volatile("s_waitcnt vmcnt(0)" ::: "memory")
#define LGKM0  asm volatile("s_waitcnt lgkmcnt(0)" ::: "memory")

static const long CN  = 256L * 4096L;   // 1M elems per batch-tensor
static const long PtE = 4096L * 4096L;  // 16M elems

// ---------------------------------------------------------------------------
// NT GEMM core (round 6, proven best): 256 thr = 4 waves (2x2); block tile
// 128x128; wave 64x64; BK=64; 2-buf counted-vmcnt pipeline; 3-bit chunk-XOR
// swizzle (0 bank conflicts measured). A and B both LDS-staged via
// global_load_lds (fully coalesced; beats A-in-register variants r10-r12).
// ---------------------------------------------------------------------------
DEVINL void gemm_core(const u16* __restrict__ Ag, int lda,
                      const u16* __restrict__ Bg, int ldb,
                      int kOff, int kLen, u16* As, u16* Bs, f32x4 (&acc)[4][4])
{
    int tid = threadIdx.x;
    int lane = tid & 63, w = tid >> 6;
    int wr = w >> 1, wc = w & 1;
    int kg = lane >> 4, rl = lane & 15;
    int l8 = lane >> 3, c8 = lane & 7;

    int srow = w * 32 + l8;
    int scol = (c8 ^ l8) * 8;                      // pre-swizzled source chunk
    const u16* aS = Ag + (size_t)srow * lda + kOff + scol;
    const u16* bS = Bg + (size_t)srow * ldb + kOff + scol;
    int dOff = w * 2048;

    int rl7 = rl & 7;
    int e0 = (kg ^ rl7) * 8;
    int e1 = e0 ^ 32;
    int aRow = (wr * 64 + rl) * 64;
    int bRow = (wc * 64 + rl) * 64;

    int nt = kLen >> 6;                            // kLen % 64 == 0, nt >= 2
#pragma unroll
    for (int q = 0; q < 4; ++q) {
        glds16(aS + (size_t)q * 8 * lda, As + dOff + q * 512);
        glds16(bS + (size_t)q * 8 * ldb, Bs + dOff + q * 512);
    }
#pragma unroll
    for (int q = 0; q < 4; ++q) {
        glds16(aS + (size_t)q * 8 * lda + 64, As + 8192 + dOff + q * 512);
        glds16(bS + (size_t)q * 8 * ldb + 64, Bs + 8192 + dOff + q * 512);
    }

    for (int t = 0; t < nt; ++t) {
        const u16* Ab = As + (t & 1) * 8192;
        const u16* Bb = Bs + (t & 1) * 8192;
        if (t + 1 < nt) { VMCNT8; } else { VMCNT0; }
        __builtin_amdgcn_s_barrier();
        CFENCE;
        f16x8 a0[4], b0[4], a1[4], b1[4];
#pragma unroll
        for (int i = 0; i < 4; ++i) a0[i] = ldfrag(&Ab[aRow + i * 1024 + e0]);
#pragma unroll
        for (int i = 0; i < 4; ++i) b0[i] = ldfrag(&Bb[bRow + i * 1024 + e0]);
#pragma unroll
        for (int i = 0; i < 4; ++i) a1[i] = ldfrag(&Ab[aRow + i * 1024 + e1]);
#pragma unroll
        for (int i = 0; i < 4; ++i) b1[i] = ldfrag(&Bb[bRow + i * 1024 + e1]);
        __builtin_amdgcn_s_setprio(1);
#pragma unroll
        for (int i = 0; i < 4; ++i)
#pragma unroll
            for (int j = 0; j < 4; ++j)
                acc[i][j] = __builtin_amdgcn_mfma_f32_16x16x32_f16(a0[i], b0[j], acc[i][j], 0, 0, 0);
#pragma unroll
        for (int i = 0; i < 4; ++i)
#pragma unroll
            for (int j = 0; j < 4; ++j)
                acc[i][j] = __builtin_amdgcn_mfma_f32_16x16x32_f16(a1[i], b1[j], acc[i][j], 0, 0, 0);
        __builtin_amdgcn_s_setprio(0);
        LGKM0;
        __builtin_amdgcn_s_barrier();
        CFENCE;
        if (t + 2 < nt) {
            const u16* aN = aS + (size_t)(t + 2) * 64;
            const u16* bN = bS + (size_t)(t + 2) * 64;
            u16* Ad = As + (t & 1) * 8192 + dOff;
            u16* Bd = Bs + (t & 1) * 8192 + dOff;
#pragma unroll
            for (int q = 0; q < 4; ++q) {
                glds16(aN + (size_t)q * 8 * lda, Ad + q * 512);
                glds16(bN + (size_t)q * 8 * ldb, Bd + q * 512);
            }
        }
    }
}

DEVINL void mergeMS(float& m, float& s, float om, float os) {
    float nm = fmaxf(m, om);
    s = s * __expf(m - nm) + os * __expf(om - nm);
    m = nm;
}

// ---------------------------------------------------------------------------
// St GEMM + fused column-stats epilogue. Flat grid 4096, XCD-swizzled:
// L = (P&7)*512 + P>>3;  b = L>>10, yb = (L>>5)&31, xb = L&31.
// Stats computed from the fp16-ROUNDED store values (self-consistent with
// pt8), reduced over kg (shfl) and wr (LDS), written to pmax/psum (d_out
// scratch, consumed before PV overwrites d_out).
// ---------------------------------------------------------------------------
__launch_bounds__(256, 2)
__global__ void st_gemm(const u16* __restrict__ Kt, const u16* __restrict__ Ktth,
                        u16* __restrict__ StH,
                        float* __restrict__ pmax, float* __restrict__ psum)
{
    __shared__ __align__(16) u16 As[2 * 8192];
    __shared__ __align__(16) u16 Bs[2 * 8192];
    int P = blockIdx.x;
    int L = (P & 7) * 512 + (P >> 3);
    int b = L >> 10, yb = (L >> 5) & 31, xb = L & 31;
    const u16* A = Kt   + (long)b * CN + (size_t)yb * 128 * 256;
    const u16* B = Ktth + (long)b * CN + (size_t)xb * 128 * 256;
    u16* out = StH + (long)b * PtE;
    int rowBase = yb * 128, colBase = xb * 128;

    f32x4 acc[4][4];
#pragma unroll
    for (int i = 0; i < 4; ++i)
#pragma unroll
        for (int j = 0; j < 4; ++j) acc[i][j] = (f32x4){0.f, 0.f, 0.f, 0.f};

    gemm_core(A, 256, B, 256, 0, 256, As, Bs, acc);

    int lane = threadIdx.x & 63, w = threadIdx.x >> 6;
    int wr = w >> 1, wc = w & 1, kg = lane >> 4, rl = lane & 15;

    float tm[4], ts[4];
#pragma unroll
    for (int j = 0; j < 4; ++j) { tm[j] = -3.0e38f; ts[j] = 0.f; }

#pragma unroll
    for (int i = 0; i < 4; ++i) {
        int row0 = rowBase + wr * 64 + i * 16 + kg * 4;
#pragma unroll
        for (int j = 0; j < 4; ++j) {
            int col = colBase + wc * 64 + j * 16 + rl;
            f32x4 v = acc[i][j];
#pragma unroll
            for (int r = 0; r < 4; ++r) {
                u16 h = f2h_u(v[r]);
                out[(size_t)(row0 + r) * 4096 + col] = h;
                float x = h2f_u(h);
                float nm = fmaxf(tm[j], x);
                ts[j] = ts[j] * __expf(tm[j] - nm) + __expf(x - nm);
                tm[j] = nm;
            }
        }
    }
    // merge across kg groups (rows) via shfl butterfly
#pragma unroll
    for (int j = 0; j < 4; ++j) {
        mergeMS(tm[j], ts[j], __shfl_xor(tm[j], 16, 64), __shfl_xor(ts[j], 16, 64));
        mergeMS(tm[j], ts[j], __shfl_xor(tm[j], 32, 64), __shfl_xor(ts[j], 32, 64));
    }
    // merge across wr via LDS (As is free after core)
    float* red = (float*)As;              // [2 wc][4 j][16 rl][2]
    __syncthreads();
    if (wr == 1 && lane < 16) {
#pragma unroll
        for (int j = 0; j < 4; ++j) {
            red[((wc * 4 + j) * 16 + rl) * 2 + 0] = tm[j];
            red[((wc * 4 + j) * 16 + rl) * 2 + 1] = ts[j];
        }
    }
    __syncthreads();
    if (wr == 0 && lane < 16) {
#pragma unroll
        for (int j = 0; j < 4; ++j) {
            mergeMS(tm[j], ts[j], red[((wc * 4 + j) * 16 + rl) * 2 + 0],
                                  red[((wc * 4 + j) * 16 + rl) * 2 + 1]);
            int col = colBase + wc * 64 + j * 16 + rl;
            long idx = ((long)b * 32 + yb) * 4096 + col;
            pmax[idx] = tm[j];
            psum[idx] = ts[j];
        }
    }
}

// fold 32 row-block partials -> cmax, crcp
__global__ void stats_combine(const float* __restrict__ pmax, const float* __restrict__ psum,
                              float* __restrict__ cmax, float* __restrict__ crcp)
{
    int b = blockIdx.y;
    int col = blockIdx.x * 256 + threadIdx.x;
    const float* pm = pmax + (long)b * 32 * 4096 + col;
    const float* ps = psum + (long)b * 32 * 4096 + col;
    float m = -3.0e38f, s = 0.f;
    for (int i = 0; i < 32; ++i) mergeMS(m, s, pm[i * 4096], ps[i * 4096]);
    cmax[b * 4096 + col] = m;
    crcp[b * 4096 + col] = 1.f / s;
}

// EPI 2 = split-K atomicAdd f32 (z -> {bq=z>>zshift, slice}) -- energy only
template<int EPI>
__launch_bounds__(256, 2)
__global__ void gemm512(const u16* __restrict__ A, int lda, long sAz,
                        const u16* __restrict__ B, int ldb, long sBz,
                        int K, int splitK, int zshift,
                        void* outv, int ldo, long sOz)
{
    __shared__ __align__(16) u16 As[2 * 8192];
    __shared__ __align__(16) u16 Bs[2 * 8192];
    int z = blockIdx.z;
    int bq = z >> zshift, s = z & ((1 << zshift) - 1);
    int kOff = s * splitK, kLen = splitK;
    A += sAz * bq; B += sBz * bq;
    long zo = sOz * bq;
    int rowBase = blockIdx.y * 128, colBase = blockIdx.x * 128;
    f32x4 acc[4][4];
#pragma unroll
    for (int i = 0; i < 4; ++i)
#pragma unroll
        for (int j = 0; j < 4; ++j) acc[i][j] = (f32x4){0.f, 0.f, 0.f, 0.f};

    gemm_core(A + (size_t)rowBase * lda, lda, B + (size_t)colBase * ldb, ldb, kOff, kLen, As, Bs, acc);

    int lane = threadIdx.x & 63, w = threadIdx.x >> 6;
    int wr = w >> 1, wc = w & 1, kg = lane >> 4, rl = lane & 15;
    float* outf = (float*)outv;
#pragma unroll
    for (int i = 0; i < 4; ++i) {
        int row0 = rowBase + wr * 64 + i * 16 + kg * 4;
#pragma unroll
        for (int j = 0; j < 4; ++j) {
            int col = colBase + wc * 64 + j * 16 + rl;
            f32x4 v = acc[i][j];
#pragma unroll
            for (int r = 0; r < 4; ++r) {
                size_t o = (size_t)(row0 + r) * ldo + col;
                atomicAdd(&outf[zo + o], v[r]);
            }
        }
    }
}

// all 16 projections in one dispatch: z = b*4 + t, out[n][o] fp16 + bias
__launch_bounds__(256, 2)
__global__ void proj_all(const u16* __restrict__ xT, const u16* __restrict__ xthT,
                         const u16* __restrict__ wts,
                         const float* __restrict__ b0, const float* __restrict__ b1,
                         const float* __restrict__ b2, const float* __restrict__ b3,
                         u16* o0, u16* o1, u16* o2, u16* o3)
{
    __shared__ __align__(16) u16 As[2 * 8192];
    __shared__ __align__(16) u16 Bs[2 * 8192];
    int z = blockIdx.z, b = z >> 2, t = z & 3;
    const u16* A = ((t & 1) ? xthT : xT) + (long)b * CN;
    const u16* B = wts + t * 65536;
    u16* out = t == 0 ? o0 + (long)b * CN : t == 1 ? o1 + (long)b * CN
             : t == 2 ? o2 + (long)b * 2 * CN : o3 + (long)b * 2 * CN;
    int rowBase = blockIdx.y * 128, colBase = blockIdx.x * 128;
    f32x4 acc[4][4];
#pragma unroll
    for (int i = 0; i < 4; ++i)
#pragma unroll
        for (int j = 0; j < 4; ++j) acc[i][j] = (f32x4){0.f, 0.f, 0.f, 0.f};

    gemm_core(A + (size_t)rowBase * 256, 256, B + (size_t)colBase * 256, 256, 0, 256, As, Bs, acc);

    const float* bias = t == 0 ? b0 : t == 1 ? b1 : t == 2 ? b2 : b3;
    int lane = threadIdx.x & 63, w = threadIdx.x >> 6;
    int wr = w >> 1, wc = w & 1, kg = lane >> 4, rl = lane & 15;
#pragma unroll
    for (int i = 0; i < 4; ++i) {
        int row0 = rowBase + wr * 64 + i * 16 + kg * 4;
#pragma unroll
        for (int j = 0; j < 4; ++j) {
            int col = colBase + wc * 64 + j * 16 + rl;
            f32x4 v = acc[i][j];
#pragma unroll
            for (int r = 0; r < 4; ++r)
                out[(size_t)(row0 + r) * 256 + col] = f2h_u(v[r] + bias[col]);
        }
    }
}

// ---------------------------------------------------------------------------
// Fused apply GEMM, flat XCD-swizzled grid (512 blocks).
// MODE 0 (PV):      L = (P&7)*64 + P>>3; b=L>>7, n=(L>>2)&31, y=(L>>1)&1, t=L&1
// MODE 1 (channel): b=L>>7, t=(L>>6)&1, n=(L>>1)&31, y=L&1
// out = gamma*(A.B^T) + src
// ---------------------------------------------------------------------------
template<int MODE>
__launch_bounds__(256, 2)
__global__ void gemm_fused(const u16* __restrict__ Abase, const u16* __restrict__ Bbase,
                           const float* __restrict__ g0p, const float* __restrict__ g1p,
                           const float* __restrict__ src0, const float* __restrict__ src1,
                           float* __restrict__ out0, float* __restrict__ out1)
{
    __shared__ __align__(16) u16 As[2 * 8192];
    __shared__ __align__(16) u16 Bs[2 * 8192];
    int P = blockIdx.x;
    int L = (P & 7) * 64 + (P >> 3);
    int b, n, y, t;
    const u16 *A, *B;
    int lda, ldb, K;
    if (MODE == 0) {
        b = L >> 7; n = (L >> 2) & 31; y = (L >> 1) & 1; t = L & 1;
        A = Abase + ((long)b * 2 + t) * CN;  lda = 4096;   // V2[b][t]
        B = Bbase + (long)b * PtE;           ldb = 4096;   // Pt[b]
        K = 4096;
    } else {
        b = L >> 7; t = (L >> 6) & 1; n = (L >> 1) & 31; y = L & 1;
        A = Abase + (long)b * 65536;         lda = 256;    // simc[b]
        B = Bbase + ((long)b * 2 + t) * CN;  ldb = 256;    // Vt2[b][t]
        K = 256;
    }
    const float* src = (t ? src1 : src0) + (long)b * CN;
    float* out = (t ? out1 : out0) + (long)b * CN;
    int rowBase = y * 128, colBase = n * 128;

    f32x4 acc[4][4];
#pragma unroll
    for (int i = 0; i < 4; ++i)
#pragma unroll
        for (int j = 0; j < 4; ++j) acc[i][j] = (f32x4){0.f, 0.f, 0.f, 0.f};

    gemm_core(A + (size_t)rowBase * lda, lda, B + (size_t)colBase * ldb, ldb, 0, K, As, Bs, acc);

    float gamma = t ? *g1p : *g0p;     // after core: keeps in-loop vmcnt exact
    int lane = threadIdx.x & 63, w = threadIdx.x >> 6;
    int wr = w >> 1, wc = w & 1, kg = lane >> 4, rl = lane & 15;
#pragma unroll
    for (int i = 0; i < 4; ++i) {
        int row0 = rowBase + wr * 64 + i * 16 + kg * 4;
#pragma unroll
        for (int j = 0; j < 4; ++j) {
            int col = colBase + wc * 64 + j * 16 + rl;
            f32x4 v = acc[i][j];
#pragma unroll
            for (int r = 0; r < 4; ++r) {
                int row = row0 + r;
                out[(size_t)row * 4096 + col] = gamma * v[r] + src[(size_t)row * 4096 + col];
            }
        }
    }
}

// f32 [R][NC] -> fp16 [NC][R] transpose; z = 2 tensors x 4 batches
__global__ void tr_f32_h2(const float* __restrict__ in0, const float* __restrict__ in1,
                          u16* __restrict__ out0, u16* __restrict__ out1)
{
    int z = blockIdx.z, b = z & 3;
    const float* in = ((z >> 2) ? in1 : in0) + (long)b * CN;
    u16* out = ((z >> 2) ? out1 : out0) + (long)b * CN;
    __shared__ u16 s[64 * 65];
    int tx = threadIdx.x & 63, tw = threadIdx.x >> 6;
    int r0 = blockIdx.y * 64, c0 = blockIdx.x * 64;
#pragma unroll
    for (int p = 0; p < 16; ++p) {
        int r = tw + p * 4;
        s[tx * 65 + r] = f2h_u(in[(size_t)(r0 + r) * 4096 + c0 + tx]);
    }
    __syncthreads();
#pragma unroll
    for (int p = 0; p < 16; ++p) {
        int rr = tw + p * 4;
        out[(size_t)(c0 + rr) * 256 + r0 + tx] = s[rr * 65 + tx];
    }
}

// fp16 [R][NC] -> fp16 [NC][R]
__global__ void tr_h_h(const u16* __restrict__ in, u16* __restrict__ out,
                       int R, int NC_, long sIn, long sOut)
{
    in += (long)blockIdx.z * sIn; out += (long)blockIdx.z * sOut;
    __shared__ u16 s[64 * 65];
    int tx = threadIdx.x & 63, tw = threadIdx.x >> 6;
    int r0 = blockIdx.y * 64, c0 = blockIdx.x * 64;
#pragma unroll
    for (int p = 0; p < 16; ++p) {
        int r = tw + p * 4;
        s[tx * 65 + r] = in[(size_t)(r0 + r) * NC_ + c0 + tx];
    }
    __syncthreads();
#pragma unroll
    for (int p = 0; p < 16; ++p) {
        int rr = tw + p * 4;
        out[(size_t)(c0 + rr) * R + r0 + tx] = s[rr * 65 + tx];
    }
}

__global__ void cvt_w_kernel(const float* __restrict__ w0, const float* __restrict__ w1,
                             const float* __restrict__ w2, const float* __restrict__ w3,
                             u16* __restrict__ out)
{
    int i = blockIdx.x * 256 + threadIdx.x;
    const float* w = (i < 65536) ? w0 : (i < 131072) ? w1 : (i < 196608) ? w2 : w3;
    out[i] = f2h_u(w[i & 65535]);
}

// in-place Pt[m,n] = fp16( exp(St[m,n]-cmax[n]) * crcp[n] ), 8 cols/thread
__global__ void pt8_kernel(u16* St, const float* __restrict__ cmax,
                           const float* __restrict__ crcp)
{
    int b = blockIdx.z;
    St += (long)b * PtE;
    cmax += b * 4096; crcp += b * 4096;
    int m = blockIdx.y;
    int c0 = (blockIdx.x * 256 + threadIdx.x) * 8;
    size_t o = (size_t)m * 4096 + c0;
    f16x8 hv = __builtin_bit_cast(f16x8, *(const int4*)(St + o));
    union { u16 q[8]; int4 v; } pk;
#pragma unroll
    for (int j = 0; j < 8; ++j)
        pk.q[j] = f2h_u(__expf((float)hv[j] - cmax[c0 + j]) * crcp[c0 + j]);
    *(int4*)(St + o) = pk.v;
}

DEVINL float blockReduce(float v, int op) {  // op 0 = max, 1 = sum; 256 threads
    __shared__ float s[4];
#pragma unroll
    for (int o = 32; o; o >>= 1) {
        float t = __shfl_xor(v, o, 64);
        v = op ? (v + t) : fmaxf(v, t);
    }
    __syncthreads();
    if ((threadIdx.x & 63) == 0) s[threadIdx.x >> 6] = v;
    __syncthreads();
    return op ? (s[0] + s[1] + s[2] + s[3]) : fmaxf(fmaxf(s[0], s[1]), fmaxf(s[2], s[3]));
}

// sim_c row softmax of (rowmax(E) - E) over d; E f32 [b][256][256]
__global__ void simc_kernel(const float* __restrict__ E, u16* __restrict__ simc)
{
    int bb = blockIdx.y;
    const float* Eb = E + bb * 65536;
    u16* sc = simc + bb * 65536;
    int c = blockIdx.x, d = threadIdx.x;
    float e = Eb[c * 256 + d];
    float rmax = blockReduce(e, 0);
    float v = rmax - e;
    float vmax = blockReduce(v, 0);
    float p = __expf(v - vmax);
    float s = blockReduce(p, 1);
    sc[c * 256 + d] = f2h_u(p / s);
}

extern "C" void kernel_launch(void* const* d_in, const int* in_sizes, int n_in,
                              void* d_out, int out_size, void* d_ws, size_t ws_size,
                              hipStream_t stream)
{
    const float* x      = (const float*)d_in[0];
    const float* xth    = (const float*)d_in[1];
    const float* Wk_rgb = (const float*)d_in[2];
    const float* bk_rgb = (const float*)d_in[3];
    const float* Wk_th  = (const float*)d_in[4];
    const float* bk_th  = (const float*)d_in[5];
    const float* Wv_rgb = (const float*)d_in[6];
    const float* bv_rgb = (const float*)d_in[7];
    const float* Wv_th  = (const float*)d_in[8];
    const float* bv_th  = (const float*)d_in[9];
    const float* g1r = (const float*)d_in[10];
    const float* g1t = (const float*)d_in[11];
    const float* g2r = (const float*)d_in[12];
    const float* g2t = (const float*)d_in[13];

    // ws carve-up (~176.5 MB)
    u16* wts   = (u16*)d_ws;             // [4][256][256] fp16
    u16* Kt    = wts + 4 * 65536;        // [4][4096][256] x_k^T  (dead after St GEMM)
    u16* Ktth  = Kt + 4 * CN;
    u16* Vt2   = Ktth + 4 * CN;          // [4][2][4096][256] (t=0: x_v^T, 1: x_v_th^T)
    u16* V2    = Vt2 + 8 * CN;           // [4][2][256][4096]
    u16* StH   = V2 + 8 * CN;            // [4][4096][4096] fp16 St -> Pt in place (128 MB)
    // small buffers alias the dead-after-St Kt region (written post-St only)
    u16* simc   = Kt;                    // [4][256][256] fp16
    float* E    = (float*)(Kt + 4 * 65536);  // [4][256][256] f32
    u16* xT    = StH;                    // alias: dead before first StH write
    u16* xthT  = xT + 4 * CN;

    float* outX2  = (float*)d_out;
    float* outXt2 = outX2 + 4 * CN;

    // softmax stats live in d_out scratch (dead until PV writes d_out):
    // pmax [4][32][4096], psum [4][32][4096], cmax/crcp [4][4096]
    float* pmax = outX2;
    float* psum = pmax + 4 * 32 * 4096;
    float* cmax = psum + 4 * 32 * 4096;
    float* crcp = cmax + 4 * 4096;

    cvt_w_kernel<<<1024, 256, 0, stream>>>(Wk_rgb, Wk_th, Wv_rgb, Wv_th, wts);
    tr_f32_h2<<<dim3(64, 4, 8), 256, 0, stream>>>(x, xth, xT, xthT);

    // all 16 projections, one dispatch (1024 blocks, 2/CU)
    proj_all<<<dim3(2, 32, 16), 256, 0, stream>>>(xT, xthT, wts,
        bk_rgb, bk_th, bv_rgb, bv_th, Kt, Ktth, Vt2, Vt2 + CN);

    tr_h_h<<<dim3(4, 64, 8), 256, 0, stream>>>(Vt2, V2, 4096, 256, CN, CN);

    // St[b][m][n] = Kt[b][m][.] . Ktth[b][n][.]  + fused column stats
    st_gemm<<<4096, 256, 0, stream>>>(Kt, Ktth, StH, pmax, psum);
    stats_combine<<<dim3(16, 4), 256, 0, stream>>>(pmax, psum, cmax, crcp);
    pt8_kernel<<<dim3(2, 4096, 4), 256, 0, stream>>>(StH, cmax, crcp);

    // x_1 = gamma1 * (V @ P) + x   (flat 512 blocks, XCD-swizzled)
    gemm_fused<0><<<512, 256, 0, stream>>>(
        V2, StH, g1r, g1t, x, xth, outX2, outXt2);

    // energy[c,d] = sum_n Vth[c,n] V[d,n]; split-K (32 slices of 128) x 4 batches
    (void)hipMemsetAsync(E, 0, 4 * 65536 * sizeof(float), stream);
    gemm512<2><<<dim3(2, 2, 128), 256, 0, stream>>>(
        V2 + CN, 4096, 2 * CN, V2, 4096, 2 * CN,
        4096, 128, 5, E, 256, 65536);
    simc_kernel<<<dim3(256, 4), 256, 0, stream>>>(E, simc);

    // x_2 = gamma2 * (simc @ V) + x_1   (in-place on d_out, flat 512 blocks)
    gemm_fused<1><<<512, 256, 0, stream>>>(
        simc, Vt2, g2r, g2t, outX2, outXt2, outX2, outXt2);
}

// Round 14
// 267.262 us; speedup vs baseline: 2.3935x; 1.0086x over previous
//
#include <hip/hip_runtime.h>

typedef unsigned short u16;
typedef __attribute__((ext_vector_type(8))) _Float16 f16x8;
typedef __attribute__((ext_vector_type(4))) float f32x4;

#define DEVINL __device__ __forceinline__
#define LOG2E 1.44269504f

DEVINL u16 f2h_u(float f) { _Float16 h = (_Float16)f; return __builtin_bit_cast(unsigned short, h); }
DEVINL float h2f_u(u16 h) { return (float)__builtin_bit_cast(_Float16, h); }
DEVINL float ex2(float x) { return __builtin_amdgcn_exp2f(x); }

DEVINL f16x8 ldfrag(const u16* p) {
    int4 d = *(const int4*)p;                 // ds_read_b128
    return __builtin_bit_cast(f16x8, d);
}

DEVINL void glds16(const u16* g, u16* l) {    // async global->LDS, 16B/lane
    __builtin_amdgcn_global_load_lds(
        (const __attribute__((address_space(1))) unsigned int*)g,
        (__attribute__((address_space(3))) unsigned int*)l, 16, 0, 0);
}

#define CFENCE asm volatile("" ::: "memory")
#define VMCNT8 asm volatile("s_waitcnt vmcnt(8)" ::: "memory")
#define VMCNT0 asm volatile("s_waitcnt vmcnt(0)" ::: "memory")
#define LGKM0  asm volatile("s_waitcnt lgkmcnt(0)" ::: "memory")

static const long CN  = 256L * 4096L;   // 1M elems per batch-tensor
static const long PtE = 4096L * 4096L;  // 16M elems

// ---------------------------------------------------------------------------
// NT GEMM core (round 6, proven best): 256 thr = 4 waves (2x2); block tile
// 128x128; wave 64x64; BK=64; 2-buf counted-vmcnt pipeline; 3-bit chunk-XOR
// swizzle (0 bank conflicts measured). A and B both LDS-staged via
// global_load_lds (fully coalesced; beats A-in-register variants r10-r12).
// ---------------------------------------------------------------------------
DEVINL void gemm_core(const u16* __restrict__ Ag, int lda,
                      const u16* __restrict__ Bg, int ldb,
                      int kOff, int kLen, u16* As, u16* Bs, f32x4 (&acc)[4][4])
{
    int tid = threadIdx.x;
    int lane = tid & 63, w = tid >> 6;
    int wr = w >> 1, wc = w & 1;
    int kg = lane >> 4, rl = lane & 15;
    int l8 = lane >> 3, c8 = lane & 7;

    int srow = w * 32 + l8;
    int scol = (c8 ^ l8) * 8;                      // pre-swizzled source chunk
    const u16* aS = Ag + (size_t)srow * lda + kOff + scol;
    const u16* bS = Bg + (size_t)srow * ldb + kOff + scol;
    int dOff = w * 2048;

    int rl7 = rl & 7;
    int e0 = (kg ^ rl7) * 8;
    int e1 = e0 ^ 32;
    int aRow = (wr * 64 + rl) * 64;
    int bRow = (wc * 64 + rl) * 64;

    int nt = kLen >> 6;                            // kLen % 64 == 0, nt >= 2
#pragma unroll
    for (int q = 0; q < 4; ++q) {
        glds16(aS + (size_t)q * 8 * lda, As + dOff + q * 512);
        glds16(bS + (size_t)q * 8 * ldb, Bs + dOff + q * 512);
    }
#pragma unroll
    for (int q = 0; q < 4; ++q) {
        glds16(aS + (size_t)q * 8 * lda + 64, As + 8192 + dOff + q * 512);
        glds16(bS + (size_t)q * 8 * ldb + 64, Bs + 8192 + dOff + q * 512);
    }

    for (int t = 0; t < nt; ++t) {
        const u16* Ab = As + (t & 1) * 8192;
        const u16* Bb = Bs + (t & 1) * 8192;
        if (t + 1 < nt) { VMCNT8; } else { VMCNT0; }
        __builtin_amdgcn_s_barrier();
        CFENCE;
        f16x8 a0[4], b0[4], a1[4], b1[4];
#pragma unroll
        for (int i = 0; i < 4; ++i) a0[i] = ldfrag(&Ab[aRow + i * 1024 + e0]);
#pragma unroll
        for (int i = 0; i < 4; ++i) b0[i] = ldfrag(&Bb[bRow + i * 1024 + e0]);
#pragma unroll
        for (int i = 0; i < 4; ++i) a1[i] = ldfrag(&Ab[aRow + i * 1024 + e1]);
#pragma unroll
        for (int i = 0; i < 4; ++i) b1[i] = ldfrag(&Bb[bRow + i * 1024 + e1]);
        __builtin_amdgcn_s_setprio(1);
#pragma unroll
        for (int i = 0; i < 4; ++i)
#pragma unroll
            for (int j = 0; j < 4; ++j)
                acc[i][j] = __builtin_amdgcn_mfma_f32_16x16x32_f16(a0[i], b0[j], acc[i][j], 0, 0, 0);
#pragma unroll
        for (int i = 0; i < 4; ++i)
#pragma unroll
            for (int j = 0; j < 4; ++j)
                acc[i][j] = __builtin_amdgcn_mfma_f32_16x16x32_f16(a1[i], b1[j], acc[i][j], 0, 0, 0);
        __builtin_amdgcn_s_setprio(0);
        LGKM0;
        __builtin_amdgcn_s_barrier();
        CFENCE;
        if (t + 2 < nt) {
            const u16* aN = aS + (size_t)(t + 2) * 64;
            const u16* bN = bS + (size_t)(t + 2) * 64;
            u16* Ad = As + (t & 1) * 8192 + dOff;
            u16* Bd = Bs + (t & 1) * 8192 + dOff;
#pragma unroll
            for (int q = 0; q < 4; ++q) {
                glds16(aN + (size_t)q * 8 * lda, Ad + q * 512);
                glds16(bN + (size_t)q * 8 * ldb, Bd + q * 512);
            }
        }
    }
}

DEVINL void mergeMS(float& m, float& s, float om, float os) {
    float nm = fmaxf(m, om);
    s = s * __expf(m - nm) + os * __expf(om - nm);
    m = nm;
}

// ---------------------------------------------------------------------------
// St GEMM + fused column-stats epilogue (TWO-PASS, r12-refcheck'd numerics):
// pass 0: round+store, keep rounded f32 in regs; pass 1: per-j max (ILP-4
// fmax chains); pass 2: 64 INDEPENDENT exp2 accumulations. Replaces r13's
// 64-deep serial online chain (~1400 dep-cycles -> ~250).
// Flat grid 4096, XCD-swizzled: L=(P&7)*512+P>>3; b=L>>10, yb=(L>>5)&31, xb=L&31.
// ---------------------------------------------------------------------------
__launch_bounds__(256, 2)
__global__ void st_gemm(const u16* __restrict__ Kt, const u16* __restrict__ Ktth,
                        u16* __restrict__ StH,
                        float* __restrict__ pmax, float* __restrict__ psum)
{
    __shared__ __align__(16) u16 As[2 * 8192];
    __shared__ __align__(16) u16 Bs[2 * 8192];
    int P = blockIdx.x;
    int L = (P & 7) * 512 + (P >> 3);
    int b = L >> 10, yb = (L >> 5) & 31, xb = L & 31;
    const u16* A = Kt   + (long)b * CN + (size_t)yb * 128 * 256;
    const u16* B = Ktth + (long)b * CN + (size_t)xb * 128 * 256;
    u16* out = StH + (long)b * PtE;
    int rowBase = yb * 128, colBase = xb * 128;

    f32x4 acc[4][4];
#pragma unroll
    for (int i = 0; i < 4; ++i)
#pragma unroll
        for (int j = 0; j < 4; ++j) acc[i][j] = (f32x4){0.f, 0.f, 0.f, 0.f};

    gemm_core(A, 256, B, 256, 0, 256, As, Bs, acc);

    int lane = threadIdx.x & 63, w = threadIdx.x >> 6;
    int wr = w >> 1, wc = w & 1, kg = lane >> 4, rl = lane & 15;

    // pass 0: round + store + keep rounded f32 (no dependent chain)
    float vr[4][4][4];
#pragma unroll
    for (int i = 0; i < 4; ++i) {
        int row0 = rowBase + wr * 64 + i * 16 + kg * 4;
#pragma unroll
        for (int j = 0; j < 4; ++j) {
            int col = colBase + wc * 64 + j * 16 + rl;
            f32x4 v = acc[i][j];
#pragma unroll
            for (int r = 0; r < 4; ++r) {
                u16 h = f2h_u(v[r]);
                out[(size_t)(row0 + r) * 4096 + col] = h;
                vr[i][j][r] = h2f_u(h);
            }
        }
    }
    // pass 1: per-j max; pass 2: independent exp2 sums
    float tm[4], ts[4];
#pragma unroll
    for (int j = 0; j < 4; ++j) {
        float m = vr[0][j][0];
#pragma unroll
        for (int i = 0; i < 4; ++i)
#pragma unroll
            for (int r = 0; r < 4; ++r) m = fmaxf(m, vr[i][j][r]);
        float mk = m * LOG2E, s = 0.f;
#pragma unroll
        for (int i = 0; i < 4; ++i)
#pragma unroll
            for (int r = 0; r < 4; ++r) s += ex2(fmaf(vr[i][j][r], LOG2E, -mk));
        tm[j] = m; ts[j] = s;
    }
    // merge across kg groups (rows) via shfl butterfly
#pragma unroll
    for (int j = 0; j < 4; ++j) {
        mergeMS(tm[j], ts[j], __shfl_xor(tm[j], 16, 64), __shfl_xor(ts[j], 16, 64));
        mergeMS(tm[j], ts[j], __shfl_xor(tm[j], 32, 64), __shfl_xor(ts[j], 32, 64));
    }
    // merge across wr via LDS (As is free after core)
    float* red = (float*)As;              // [2 wc][4 j][16 rl][2]
    __syncthreads();
    if (wr == 1 && lane < 16) {
#pragma unroll
        for (int j = 0; j < 4; ++j) {
            red[((wc * 4 + j) * 16 + rl) * 2 + 0] = tm[j];
            red[((wc * 4 + j) * 16 + rl) * 2 + 1] = ts[j];
        }
    }
    __syncthreads();
    if (wr == 0 && lane < 16) {
#pragma unroll
        for (int j = 0; j < 4; ++j) {
            mergeMS(tm[j], ts[j], red[((wc * 4 + j) * 16 + rl) * 2 + 0],
                                  red[((wc * 4 + j) * 16 + rl) * 2 + 1]);
            int col = colBase + wc * 64 + j * 16 + rl;
            long idx = ((long)b * 32 + yb) * 4096 + col;
            pmax[idx] = tm[j];
            psum[idx] = ts[j];
        }
    }
}

// fold 32 row-block partials -> cmax, crcp
__global__ void stats_combine(const float* __restrict__ pmax, const float* __restrict__ psum,
                              float* __restrict__ cmax, float* __restrict__ crcp)
{
    int b = blockIdx.y;
    int col = blockIdx.x * 256 + threadIdx.x;
    const float* pm = pmax + (long)b * 32 * 4096 + col;
    const float* ps = psum + (long)b * 32 * 4096 + col;
    float m = -3.0e38f, s = 0.f;
    for (int i = 0; i < 32; ++i) mergeMS(m, s, pm[i * 4096], ps[i * 4096]);
    cmax[b * 4096 + col] = m;
    crcp[b * 4096 + col] = 1.f / s;
}

// EPI 2 = split-K atomicAdd f32 (z -> {bq=z>>zshift, slice}) -- energy only
template<int EPI>
__launch_bounds__(256, 2)
__global__ void gemm512(const u16* __restrict__ A, int lda, long sAz,
                        const u16* __restrict__ B, int ldb, long sBz,
                        int K, int splitK, int zshift,
                        void* outv, int ldo, long sOz)
{
    __shared__ __align__(16) u16 As[2 * 8192];
    __shared__ __align__(16) u16 Bs[2 * 8192];
    int z = blockIdx.z;
    int bq = z >> zshift, s = z & ((1 << zshift) - 1);
    int kOff = s * splitK, kLen = splitK;
    A += sAz * bq; B += sBz * bq;
    long zo = sOz * bq;
    int rowBase = blockIdx.y * 128, colBase = blockIdx.x * 128;
    f32x4 acc[4][4];
#pragma unroll
    for (int i = 0; i < 4; ++i)
#pragma unroll
        for (int j = 0; j < 4; ++j) acc[i][j] = (f32x4){0.f, 0.f, 0.f, 0.f};

    gemm_core(A + (size_t)rowBase * lda, lda, B + (size_t)colBase * ldb, ldb, kOff, kLen, As, Bs, acc);

    int lane = threadIdx.x & 63, w = threadIdx.x >> 6;
    int wr = w >> 1, wc = w & 1, kg = lane >> 4, rl = lane & 15;
    float* outf = (float*)outv;
#pragma unroll
    for (int i = 0; i < 4; ++i) {
        int row0 = rowBase + wr * 64 + i * 16 + kg * 4;
#pragma unroll
        for (int j = 0; j < 4; ++j) {
            int col = colBase + wc * 64 + j * 16 + rl;
            f32x4 v = acc[i][j];
#pragma unroll
            for (int r = 0; r < 4; ++r) {
                size_t o = (size_t)(row0 + r) * ldo + col;
                atomicAdd(&outf[zo + o], v[r]);
            }
        }
    }
}

// all 16 projections in one dispatch: z = b*4 + t, out[n][o] fp16 + bias
__launch_bounds__(256, 2)
__global__ void proj_all(const u16* __restrict__ xT, const u16* __restrict__ xthT,
                         const u16* __restrict__ wts,
                         const float* __restrict__ b0, const float* __restrict__ b1,
                         const float* __restrict__ b2, const float* __restrict__ b3,
                         u16* o0, u16* o1, u16* o2, u16* o3)
{
    __shared__ __align__(16) u16 As[2 * 8192];
    __shared__ __align__(16) u16 Bs[2 * 8192];
    int z = blockIdx.z, b = z >> 2, t = z & 3;
    const u16* A = ((t & 1) ? xthT : xT) + (long)b * CN;
    const u16* B = wts + t * 65536;
    u16* out = t == 0 ? o0 + (long)b * CN : t == 1 ? o1 + (long)b * CN
             : t == 2 ? o2 + (long)b * 2 * CN : o3 + (long)b * 2 * CN;
    int rowBase = blockIdx.y * 128, colBase = blockIdx.x * 128;
    f32x4 acc[4][4];
#pragma unroll
    for (int i = 0; i < 4; ++i)
#pragma unroll
        for (int j = 0; j < 4; ++j) acc[i][j] = (f32x4){0.f, 0.f, 0.f, 0.f};

    gemm_core(A + (size_t)rowBase * 256, 256, B + (size_t)colBase * 256, 256, 0, 256, As, Bs, acc);

    const float* bias = t == 0 ? b0 : t == 1 ? b1 : t == 2 ? b2 : b3;
    int lane = threadIdx.x & 63, w = threadIdx.x >> 6;
    int wr = w >> 1, wc = w & 1, kg = lane >> 4, rl = lane & 15;
#pragma unroll
    for (int i = 0; i < 4; ++i) {
        int row0 = rowBase + wr * 64 + i * 16 + kg * 4;
#pragma unroll
        for (int j = 0; j < 4; ++j) {
            int col = colBase + wc * 64 + j * 16 + rl;
            f32x4 v = acc[i][j];
#pragma unroll
            for (int r = 0; r < 4; ++r)
                out[(size_t)(row0 + r) * 256 + col] = f2h_u(v[r] + bias[col]);
        }
    }
}

// ---------------------------------------------------------------------------
// Fused apply GEMM, flat XCD-swizzled grid (512 blocks).
// MODE 0 (PV):      L = (P&7)*64 + P>>3; b=L>>7, n=(L>>2)&31, y=(L>>1)&1, t=L&1
// MODE 1 (channel): b=L>>7, t=(L>>6)&1, n=(L>>1)&31, y=L&1
// out = gamma*(A.B^T) + src
// ---------------------------------------------------------------------------
template<int MODE>
__launch_bounds__(256, 2)
__global__ void gemm_fused(const u16* __restrict__ Abase, const u16* __restrict__ Bbase,
                           const float* __restrict__ g0p, const float* __restrict__ g1p,
                           const float* __restrict__ src0, const float* __restrict__ src1,
                           float* __restrict__ out0, float* __restrict__ out1)
{
    __shared__ __align__(16) u16 As[2 * 8192];
    __shared__ __align__(16) u16 Bs[2 * 8192];
    int P = blockIdx.x;
    int L = (P & 7) * 64 + (P >> 3);
    int b, n, y, t;
    const u16 *A, *B;
    int lda, ldb, K;
    if (MODE == 0) {
        b = L >> 7; n = (L >> 2) & 31; y = (L >> 1) & 1; t = L & 1;
        A = Abase + ((long)b * 2 + t) * CN;  lda = 4096;   // V2[b][t]
        B = Bbase + (long)b * PtE;           ldb = 4096;   // Pt[b]
        K = 4096;
    } else {
        b = L >> 7; t = (L >> 6) & 1; n = (L >> 1) & 31; y = L & 1;
        A = Abase + (long)b * 65536;         lda = 256;    // simc[b]
        B = Bbase + ((long)b * 2 + t) * CN;  ldb = 256;    // Vt2[b][t]
        K = 256;
    }
    const float* src = (t ? src1 : src0) + (long)b * CN;
    float* out = (t ? out1 : out0) + (long)b * CN;
    int rowBase = y * 128, colBase = n * 128;

    f32x4 acc[4][4];
#pragma unroll
    for (int i = 0; i < 4; ++i)
#pragma unroll
        for (int j = 0; j < 4; ++j) acc[i][j] = (f32x4){0.f, 0.f, 0.f, 0.f};

    gemm_core(A + (size_t)rowBase * lda, lda, B + (size_t)colBase * ldb, ldb, 0, K, As, Bs, acc);

    float gamma = t ? *g1p : *g0p;     // after core: keeps in-loop vmcnt exact
    int lane = threadIdx.x & 63, w = threadIdx.x >> 6;
    int wr = w >> 1, wc = w & 1, kg = lane >> 4, rl = lane & 15;
#pragma unroll
    for (int i = 0; i < 4; ++i) {
        int row0 = rowBase + wr * 64 + i * 16 + kg * 4;
#pragma unroll
        for (int j = 0; j < 4; ++j) {
            int col = colBase + wc * 64 + j * 16 + rl;
            f32x4 v = acc[i][j];
#pragma unroll
            for (int r = 0; r < 4; ++r) {
                int row = row0 + r;
                out[(size_t)row * 4096 + col] = gamma * v[r] + src[(size_t)row * 4096 + col];
            }
        }
    }
}

// f32 [R][NC] -> fp16 [NC][R] transpose; z = 2 tensors x 4 batches
__global__ void tr_f32_h2(const float* __restrict__ in0, const float* __restrict__ in1,
                          u16* __restrict__ out0, u16* __restrict__ out1)
{
    int z = blockIdx.z, b = z & 3;
    const float* in = ((z >> 2) ? in1 : in0) + (long)b * CN;
    u16* out = ((z >> 2) ? out1 : out0) + (long)b * CN;
    __shared__ u16 s[64 * 65];
    int tx = threadIdx.x & 63, tw = threadIdx.x >> 6;
    int r0 = blockIdx.y * 64, c0 = blockIdx.x * 64;
#pragma unroll
    for (int p = 0; p < 16; ++p) {
        int r = tw + p * 4;
        s[tx * 65 + r] = f2h_u(in[(size_t)(r0 + r) * 4096 + c0 + tx]);
    }
    __syncthreads();
#pragma unroll
    for (int p = 0; p < 16; ++p) {
        int rr = tw + p * 4;
        out[(size_t)(c0 + rr) * 256 + r0 + tx] = s[rr * 65 + tx];
    }
}

// fp16 [R][NC] -> fp16 [NC][R]
__global__ void tr_h_h(const u16* __restrict__ in, u16* __restrict__ out,
                       int R, int NC_, long sIn, long sOut)
{
    in += (long)blockIdx.z * sIn; out += (long)blockIdx.z * sOut;
    __shared__ u16 s[64 * 65];
    int tx = threadIdx.x & 63, tw = threadIdx.x >> 6;
    int r0 = blockIdx.y * 64, c0 = blockIdx.x * 64;
#pragma unroll
    for (int p = 0; p < 16; ++p) {
        int r = tw + p * 4;
        s[tx * 65 + r] = in[(size_t)(r0 + r) * NC_ + c0 + tx];
    }
    __syncthreads();
#pragma unroll
    for (int p = 0; p < 16; ++p) {
        int rr = tw + p * 4;
        out[(size_t)(c0 + rr) * R + r0 + tx] = s[rr * 65 + tx];
    }
}

__global__ void cvt_w_kernel(const float* __restrict__ w0, const float* __restrict__ w1,
                             const float* __restrict__ w2, const float* __restrict__ w3,
                             u16* __restrict__ out)
{
    int i = blockIdx.x * 256 + threadIdx.x;
    const float* w = (i < 65536) ? w0 : (i < 131072) ? w1 : (i < 196608) ? w2 : w3;
    out[i] = f2h_u(w[i & 65535]);
}

// in-place Pt[m,n] = fp16( exp(St[m,n]-cmax[n]) * crcp[n] ), 8 cols/thread
__global__ void pt8_kernel(u16* St, const float* __restrict__ cmax,
                           const float* __restrict__ crcp)
{
    int b = blockIdx.z;
    St += (long)b * PtE;
    cmax += b * 4096; crcp += b * 4096;
    int m = blockIdx.y;
    int c0 = (blockIdx.x * 256 + threadIdx.x) * 8;
    size_t o = (size_t)m * 4096 + c0;
    f16x8 hv = __builtin_bit_cast(f16x8, *(const int4*)(St + o));
    union { u16 q[8]; int4 v; } pk;
#pragma unroll
    for (int j = 0; j < 8; ++j)
        pk.q[j] = f2h_u(__expf((float)hv[j] - cmax[c0 + j]) * crcp[c0 + j]);
    *(int4*)(St + o) = pk.v;
}

DEVINL float blockReduce(float v, int op) {  // op 0 = max, 1 = sum; 256 threads
    __shared__ float s[4];
#pragma unroll
    for (int o = 32; o; o >>= 1) {
        float t = __shfl_xor(v, o, 64);
        v = op ? (v + t) : fmaxf(v, t);
    }
    __syncthreads();
    if ((threadIdx.x & 63) == 0) s[threadIdx.x >> 6] = v;
    __syncthreads();
    return op ? (s[0] + s[1] + s[2] + s[3]) : fmaxf(fmaxf(s[0], s[1]), fmaxf(s[2], s[3]));
}

// sim_c row softmax of (rowmax(E) - E) over d; E f32 [b][256][256]
__global__ void simc_kernel(const float* __restrict__ E, u16* __restrict__ simc)
{
    int bb = blockIdx.y;
    const float* Eb = E + bb * 65536;
    u16* sc = simc + bb * 65536;
    int c = blockIdx.x, d = threadIdx.x;
    float e = Eb[c * 256 + d];
    float rmax = blockReduce(e, 0);
    float v = rmax - e;
    float vmax = blockReduce(v, 0);
    float p = __expf(v - vmax);
    float s = blockReduce(p, 1);
    sc[c * 256 + d] = f2h_u(p / s);
}

extern "C" void kernel_launch(void* const* d_in, const int* in_sizes, int n_in,
                              void* d_out, int out_size, void* d_ws, size_t ws_size,
                              hipStream_t stream)
{
    const float* x      = (const float*)d_in[0];
    const float* xth    = (const float*)d_in[1];
    const float* Wk_rgb = (const float*)d_in[2];
    const float* bk_rgb = (const float*)d_in[3];
    const float* Wk_th  = (const float*)d_in[4];
    const float* bk_th  = (const float*)d_in[5];
    const float* Wv_rgb = (const float*)d_in[6];
    const float* bv_rgb = (const float*)d_in[7];
    const float* Wv_th  = (const float*)d_in[8];
    const float* bv_th  = (const float*)d_in[9];
    const float* g1r = (const float*)d_in[10];
    const float* g1t = (const float*)d_in[11];
    const float* g2r = (const float*)d_in[12];
    const float* g2t = (const float*)d_in[13];

    // ws carve-up (~176.5 MB)
    u16* wts   = (u16*)d_ws;             // [4][256][256] fp16
    u16* Kt    = wts + 4 * 65536;        // [4][4096][256] x_k^T  (dead after St GEMM)
    u16* Ktth  = Kt + 4 * CN;
    u16* Vt2   = Ktth + 4 * CN;          // [4][2][4096][256] (t=0: x_v^T, 1: x_v_th^T)
    u16* V2    = Vt2 + 8 * CN;           // [4][2][256][4096]
    u16* StH   = V2 + 8 * CN;            // [4][4096][4096] fp16 St -> Pt in place (128 MB)
    // small buffers alias the dead-after-St Kt region (written post-St only)
    u16* simc   = Kt;                    // [4][256][256] fp16
    float* E    = (float*)(Kt + 4 * 65536);  // [4][256][256] f32
    u16* xT    = StH;                    // alias: dead before first StH write
    u16* xthT  = xT + 4 * CN;

    float* outX2  = (float*)d_out;
    float* outXt2 = outX2 + 4 * CN;

    // softmax stats live in d_out scratch (dead until PV writes d_out):
    // pmax [4][32][4096], psum [4][32][4096], cmax/crcp [4][4096]
    float* pmax = outX2;
    float* psum = pmax + 4 * 32 * 4096;
    float* cmax = psum + 4 * 32 * 4096;
    float* crcp = cmax + 4 * 4096;

    cvt_w_kernel<<<1024, 256, 0, stream>>>(Wk_rgb, Wk_th, Wv_rgb, Wv_th, wts);
    tr_f32_h2<<<dim3(64, 4, 8), 256, 0, stream>>>(x, xth, xT, xthT);

    // all 16 projections, one dispatch (1024 blocks, 2/CU)
    proj_all<<<dim3(2, 32, 16), 256, 0, stream>>>(xT, xthT, wts,
        bk_rgb, bk_th, bv_rgb, bv_th, Kt, Ktth, Vt2, Vt2 + CN);

    tr_h_h<<<dim3(4, 64, 8), 256, 0, stream>>>(Vt2, V2, 4096, 256, CN, CN);

    // St[b][m][n] = Kt[b][m][.] . Ktth[b][n][.]  + fused column stats
    st_gemm<<<4096, 256, 0, stream>>>(Kt, Ktth, StH, pmax, psum);
    stats_combine<<<dim3(16, 4), 256, 0, stream>>>(pmax, psum, cmax, crcp);
    pt8_kernel<<<dim3(2, 4096, 4), 256, 0, stream>>>(StH, cmax, crcp);

    // x_1 = gamma1 * (V @ P) + x   (flat 512 blocks, XCD-swizzled)
    gemm_fused<0><<<512, 256, 0, stream>>>(
        V2, StH, g1r, g1t, x, xth, outX2, outXt2);

    // energy[c,d] = sum_n Vth[c,n] V[d,n]; split-K (32 slices of 128) x 4 batches
    (void)hipMemsetAsync(E, 0, 4 * 65536 * sizeof(float), stream);
    gemm512<2><<<dim3(2, 2, 128), 256, 0, stream>>>(
        V2 + CN, 4096, 2 * CN, V2, 4096, 2 * CN,
        4096, 128, 5, E, 256, 65536);
    simc_kernel<<<dim3(256, 4), 256, 0, stream>>>(E, simc);

    // x_2 = gamma2 * (simc @ V) + x_1   (in-place on d_out, flat 512 blocks)
    gemm_fused<1><<<512, 256, 0, stream>>>(
        simc, Vt2, g2r, g2t, outX2, outXt2, outX2, outXt2);
}